// Round 12
// baseline (324.730 us; speedup 1.0000x reference)
//
#include <hip/hip_runtime.h>
#include <math.h>

#define NEG_SLOPE 0.2f
#define BN_EPS 1e-5f

typedef __attribute__((ext_vector_type(8))) short bf16x8;
typedef __attribute__((ext_vector_type(4))) float f32x4;

static __device__ __forceinline__ unsigned short f2bf(float f){
    unsigned u = __float_as_uint(f);
    u += 0x7FFFu + ((u >> 16) & 1u);          // round-to-nearest-even
    return (unsigned short)(u >> 16);
}
static __device__ __forceinline__ float bf2f(unsigned short v){
    return __uint_as_float((unsigned)v << 16);
}

// ---- fused prep: repack W0, W1 to MFMA B-frag hi/lo planes + deg_init ----
static __device__ __forceinline__ void repack_one(const float* __restrict__ W,
    unsigned short* __restrict__ whi, unsigned short* __restrict__ wlo, int o)
{
    const int j = o & 7, ln = (o >> 3) & 63, ct = (o >> 9) & 15, kt = o >> 13;
    const int k = kt * 32 + 8 * (ln >> 4) + j;
    const int col = ct * 16 + (ln & 15);
    const float v = W[k * 256 + col];
    const unsigned short hb = f2bf(v);
    whi[o] = hb; wlo[o] = f2bf(v - bf2f(hb));
}

__global__ void prep_kernel(const float* __restrict__ W0,
    unsigned short* __restrict__ w0hi, unsigned short* __restrict__ w0lo,
    const float* __restrict__ W1,
    unsigned short* __restrict__ w1hi, unsigned short* __restrict__ w1lo,
    int* __restrict__ deg, int N)
{
    const int bid = blockIdx.x, t = threadIdx.x;
    if (bid < 128){
        repack_one(W0, w0hi, w0lo, bid * 256 + t);
    } else if (bid < 384){
        repack_one(W1, w1hi, w1lo, (bid - 128) * 256 + t);
    } else {
        const int i = (bid - 384) * 256 + t;
        if (i < N) deg[i] = 1;                // self-loop
    }
}

// =========================================================================
// REGISTERIZED MFMA GEMMs: no LDS, no barriers. Wave = head; each wave loads
// its own B-frags (coalesced from packed layout) and the full A tile (16B/lane
// slices, 64B-segment gather) straight to registers. Waves run free; load
// latency hidden by wave-level parallelism instead of intra-block pipelining.
// C/D map (verified): col=lane&15, row=(lane>>4)*4+reg.
// =========================================================================
__global__ __launch_bounds__(256) void mfma_gemm0(
    const float* __restrict__ x,
    const unsigned short* __restrict__ wbhi, const unsigned short* __restrict__ wblo,
    const float* __restrict__ a_s, const float* __restrict__ a_d,
    unsigned short* __restrict__ hout,
    float* __restrict__ asrc, float* __restrict__ adst, int N)
{
    constexpr int K = 128;
    const int t = threadIdx.x, lane = t & 63, wid = t >> 6;
    const int n0 = blockIdx.x * 64;
    const int l15 = lane & 15, lg = lane >> 4;

    const float* ap[4];
#pragma unroll
    for (int rt = 0; rt < 4; ++rt){
        int node = n0 + rt * 16 + l15;
        if (node > N - 1) node = N - 1;       // clamp; results discarded later
        ap[rt] = &x[(size_t)node * K + 8 * lg];
    }
    const unsigned short* bph = &wbhi[((size_t)(wid * 4) * 64 + lane) * 8];
    const unsigned short* bpl = &wblo[((size_t)(wid * 4) * 64 + lane) * 8];

    f32x4 acc[4][4];
#pragma unroll
    for (int rt = 0; rt < 4; ++rt)
#pragma unroll
        for (int q = 0; q < 4; ++q) acc[rt][q] = (f32x4){0.f, 0.f, 0.f, 0.f};

#pragma unroll 2
    for (int kt = 0; kt < K / 32; ++kt){
        // B: wave-private, contiguous 16B/lane
        bf16x8 bhi[4], blo[4];
#pragma unroll
        for (int q = 0; q < 4; ++q){
            bhi[q] = *(const bf16x8*)(bph + ((size_t)kt * 16 + q) * 512);
            blo[q] = *(const bf16x8*)(bpl + ((size_t)kt * 16 + q) * 512);
        }
        // A: fp32, 32B/lane (2 x dwordx4), hi/lo split in-register
        float4 f0[4], f1[4];
#pragma unroll
        for (int rt = 0; rt < 4; ++rt){
            f0[rt] = *(const float4*)(ap[rt] + kt * 32);
            f1[rt] = *(const float4*)(ap[rt] + kt * 32 + 4);
        }
        bf16x8 ahi[4], alo[4];
#pragma unroll
        for (int rt = 0; rt < 4; ++rt){
            const float fv[8] = {f0[rt].x, f0[rt].y, f0[rt].z, f0[rt].w,
                                 f1[rt].x, f1[rt].y, f1[rt].z, f1[rt].w};
#pragma unroll
            for (int j = 0; j < 8; ++j){
                const unsigned short hb = f2bf(fv[j]);
                ahi[rt][j] = (short)hb;
                alo[rt][j] = (short)f2bf(fv[j] - bf2f(hb));
            }
        }
#pragma unroll
        for (int q = 0; q < 4; ++q)
#pragma unroll
            for (int rt = 0; rt < 4; ++rt){
                acc[rt][q] = __builtin_amdgcn_mfma_f32_16x16x32_bf16(ahi[rt], bhi[q], acc[rt][q], 0, 0, 0);
                acc[rt][q] = __builtin_amdgcn_mfma_f32_16x16x32_bf16(alo[rt], bhi[q], acc[rt][q], 0, 0, 0);
                acc[rt][q] = __builtin_amdgcn_mfma_f32_16x16x32_bf16(ahi[rt], blo[q], acc[rt][q], 0, 0, 0);
            }
    }

    // ---- epilogue: h store + alpha reductions ----
    float avs[4], avd[4];
#pragma unroll
    for (int q = 0; q < 4; ++q){
        avs[q] = a_s[wid * 64 + q * 16 + l15];
        avd[q] = a_d[wid * 64 + q * 16 + l15];
    }
    float sp[4][4], dp[4][4];
#pragma unroll
    for (int rt = 0; rt < 4; ++rt){
#pragma unroll
        for (int reg = 0; reg < 4; ++reg){
            const int node = n0 + rt * 16 + lg * 4 + reg;
            float s = 0.f, d = 0.f;
            unsigned short hv[4];
#pragma unroll
            for (int q = 0; q < 4; ++q){
                const float v = acc[rt][q][reg];
                s = fmaf(v, avs[q], s); d = fmaf(v, avd[q], d);
                hv[q] = f2bf(v);
            }
            if (node < N){
#pragma unroll
                for (int q = 0; q < 4; ++q)
                    hout[(size_t)node * 256 + (wid * 4 + q) * 16 + l15] = hv[q];
            }
            sp[rt][reg] = s; dp[rt][reg] = d;
        }
    }
#pragma unroll
    for (int off = 1; off <= 8; off <<= 1){
#pragma unroll
        for (int rt = 0; rt < 4; ++rt)
#pragma unroll
            for (int reg = 0; reg < 4; ++reg){
                sp[rt][reg] += __shfl_xor(sp[rt][reg], off, 64);
                dp[rt][reg] += __shfl_xor(dp[rt][reg], off, 64);
            }
    }
    if (l15 == 0){
#pragma unroll
        for (int rt = 0; rt < 4; ++rt)
#pragma unroll
            for (int reg = 0; reg < 4; ++reg){
                const int node = n0 + rt * 16 + lg * 4 + reg;
                if (node < N){
                    asrc[(size_t)node * 4 + wid] = sp[rt][reg];
                    adst[(size_t)node * 4 + wid] = dp[rt][reg];
                }
            }
    }
}

__global__ __launch_bounds__(256) void mfma_gemm1(
    const unsigned short* __restrict__ xb,
    const unsigned short* __restrict__ wbhi, const unsigned short* __restrict__ wblo,
    const float* __restrict__ a_s, const float* __restrict__ a_d,
    unsigned short* __restrict__ hout,
    float* __restrict__ asrc, float* __restrict__ adst, int N)
{
    constexpr int K = 256;
    const int t = threadIdx.x, lane = t & 63, wid = t >> 6;
    const int n0 = blockIdx.x * 64;
    const int l15 = lane & 15, lg = lane >> 4;

    const unsigned short* ap[4];
#pragma unroll
    for (int rt = 0; rt < 4; ++rt){
        int node = n0 + rt * 16 + l15;
        if (node > N - 1) node = N - 1;
        ap[rt] = &xb[(size_t)node * K + 8 * lg];
    }
    const unsigned short* bph = &wbhi[((size_t)(wid * 4) * 64 + lane) * 8];
    const unsigned short* bpl = &wblo[((size_t)(wid * 4) * 64 + lane) * 8];

    f32x4 acc[4][4];
#pragma unroll
    for (int rt = 0; rt < 4; ++rt)
#pragma unroll
        for (int q = 0; q < 4; ++q) acc[rt][q] = (f32x4){0.f, 0.f, 0.f, 0.f};

#pragma unroll 2
    for (int kt = 0; kt < K / 32; ++kt){
        bf16x8 bhi[4], blo[4];
#pragma unroll
        for (int q = 0; q < 4; ++q){
            bhi[q] = *(const bf16x8*)(bph + ((size_t)kt * 16 + q) * 512);
            blo[q] = *(const bf16x8*)(bpl + ((size_t)kt * 16 + q) * 512);
        }
        bf16x8 a[4];
#pragma unroll
        for (int rt = 0; rt < 4; ++rt)
            a[rt] = *(const bf16x8*)(ap[rt] + kt * 32);

#pragma unroll
        for (int q = 0; q < 4; ++q)
#pragma unroll
            for (int rt = 0; rt < 4; ++rt){
                acc[rt][q] = __builtin_amdgcn_mfma_f32_16x16x32_bf16(a[rt], bhi[q], acc[rt][q], 0, 0, 0);
                acc[rt][q] = __builtin_amdgcn_mfma_f32_16x16x32_bf16(a[rt], blo[q], acc[rt][q], 0, 0, 0);
            }
    }

    // ---- epilogue ----
    float avs[4], avd[4];
#pragma unroll
    for (int q = 0; q < 4; ++q){
        avs[q] = a_s[wid * 64 + q * 16 + l15];
        avd[q] = a_d[wid * 64 + q * 16 + l15];
    }
    float sp[4][4], dp[4][4];
#pragma unroll
    for (int rt = 0; rt < 4; ++rt){
#pragma unroll
        for (int reg = 0; reg < 4; ++reg){
            const int node = n0 + rt * 16 + lg * 4 + reg;
            float s = 0.f, d = 0.f;
            unsigned short hv[4];
#pragma unroll
            for (int q = 0; q < 4; ++q){
                const float v = acc[rt][q][reg];
                s = fmaf(v, avs[q], s); d = fmaf(v, avd[q], d);
                hv[q] = f2bf(v);
            }
            if (node < N){
#pragma unroll
                for (int q = 0; q < 4; ++q)
                    hout[(size_t)node * 256 + (wid * 4 + q) * 16 + l15] = hv[q];
            }
            sp[rt][reg] = s; dp[rt][reg] = d;
        }
    }
#pragma unroll
    for (int off = 1; off <= 8; off <<= 1){
#pragma unroll
        for (int rt = 0; rt < 4; ++rt)
#pragma unroll
            for (int reg = 0; reg < 4; ++reg){
                sp[rt][reg] += __shfl_xor(sp[rt][reg], off, 64);
                dp[rt][reg] += __shfl_xor(dp[rt][reg], off, 64);
            }
    }
    if (l15 == 0){
#pragma unroll
        for (int rt = 0; rt < 4; ++rt)
#pragma unroll
            for (int reg = 0; reg < 4; ++reg){
                const int node = n0 + rt * 16 + lg * 4 + reg;
                if (node < N){
                    asrc[(size_t)node * 4 + wid] = sp[rt][reg];
                    adst[(size_t)node * 4 + wid] = dp[rt][reg];
                }
            }
    }
}

// ============================ CSR build (once) ============================
__global__ void deg_hist_kernel(const int* __restrict__ ei, int E, int* __restrict__ deg){
    int e = blockIdx.x * blockDim.x + threadIdx.x;
    if (e < E) atomicAdd(&deg[ei[E + e]], 1);
}

__global__ __launch_bounds__(256) void part_sum_kernel(const int* __restrict__ deg,
                                                       int* __restrict__ bsum, int N)
{
    __shared__ int red[256];
    const int t = threadIdx.x;
    const int i0 = blockIdx.x * 1024 + t * 4;
    int s = 0;
    if (i0 + 3 < N){
        const int4 v = *(const int4*)&deg[i0];
        s = v.x + v.y + v.z + v.w;
    } else {
#pragma unroll
        for (int j = 0; j < 4; ++j) if (i0 + j < N) s += deg[i0 + j];
    }
    red[t] = s; __syncthreads();
    for (int off = 128; off >= 1; off >>= 1){
        if (t < off) red[t] += red[t + off];
        __syncthreads();
    }
    if (t == 0) bsum[blockIdx.x] = red[0];
}

__global__ __launch_bounds__(256) void scan_part_kernel(int* __restrict__ bsum, int nb,
                                                        int* __restrict__ row, int N)
{
    __shared__ int sh[256];
    const int t = threadIdx.x;
    const int v = (t < nb) ? bsum[t] : 0;
    sh[t] = v; __syncthreads();
    for (int off = 1; off < 256; off <<= 1){
        int u = (t >= off) ? sh[t - off] : 0;
        __syncthreads();
        sh[t] += u;
        __syncthreads();
    }
    if (t < nb) bsum[t] = sh[t] - v;              // exclusive
    if (t == nb - 1) row[N] = sh[t];              // total = E + N
}

__global__ __launch_bounds__(256) void distribute_kernel(const int* __restrict__ deg,
    const int* __restrict__ bsum, int* __restrict__ row, int* __restrict__ cursor, int N)
{
    __shared__ int ts[256];
    const int t = threadIdx.x;
    const int i0 = blockIdx.x * 1024 + t * 4;
    int d[4]; int s = 0;
#pragma unroll
    for (int j = 0; j < 4; ++j){ d[j] = (i0 + j < N) ? deg[i0 + j] : 0; s += d[j]; }
    ts[t] = s; __syncthreads();
    for (int off = 1; off < 256; off <<= 1){
        int u = (t >= off) ? ts[t - off] : 0;
        __syncthreads();
        ts[t] += u;
        __syncthreads();
    }
    int base = bsum[blockIdx.x] + ts[t] - s;
#pragma unroll
    for (int j = 0; j < 4; ++j){
        if (i0 + j < N){ row[i0 + j] = base; cursor[i0 + j] = base; base += d[j]; }
    }
}

__global__ void scatter_kernel(const int* __restrict__ ei, int E, int N,
                               int* __restrict__ cursor, int* __restrict__ csr)
{
    int e = blockIdx.x * blockDim.x + threadIdx.x;
    if (e >= E + N) return;
    int s, d;
    if (e < E){ s = ei[e]; d = ei[E + e]; } else { s = d = e - E; }
    int pos = atomicAdd(&cursor[d], 1);
    csr[pos] = s;
}

// =========================================================================
// Gather-aggregate: one wave per node, 4 waves/block. h [node][256] bf16;
// lane owns (head = lane>>4, channels 4*lane..4*lane+3).
// Phase A: lane-parallel p=exp(leakyrelu(e)) -> LDS + denom butterfly.
// Phase B: 2-unrolled gather via byte offsets (VGPR-lean, 70% occ).
//   LAST=false: write P0 bf16. LAST=true: +res, h2 = P1.W2 -> outh2[node].
// =========================================================================
#define DEG_CAP 128
template<bool LAST>
__global__ __launch_bounds__(256) void agg4_kernel(
    const int* __restrict__ row, const int* __restrict__ csr,
    const float* __restrict__ asrc, const float* __restrict__ adst,
    const unsigned short* __restrict__ h,
    const float* __restrict__ b, const float* __restrict__ g,
    const float* __restrict__ be, const float* __restrict__ mean,
    const float* __restrict__ var,
    const unsigned short* __restrict__ res,   // bf16 residual (LAST only)
    unsigned short* __restrict__ outbf,       // P0 bf16 (layer0)
    float* __restrict__ outh2,                // h2 (LAST)
    const float* __restrict__ W2,             // LAST only
    int N)
{
    __shared__ float plds[4][DEG_CAP * 4];
    __shared__ int   slds[4][DEG_CAP];
    const int wid = threadIdx.x >> 6, lane = threadIdx.x & 63;
    const int node = blockIdx.x * 4 + wid;
    if (node >= N) return;
    const int beg = row[node], end = row[node + 1], deg = end - beg;
    const int degc = deg < DEG_CAP ? deg : DEG_CAP;
    const int head = lane >> 4;

    const float4 ad = *(const float4*)&adst[(size_t)node * 4];

    // ---- phase A ----
    float d0 = 0.f, d1 = 0.f, d2 = 0.f, d3 = 0.f;
    for (int i = lane; i < deg; i += 64){
        const int s = csr[beg + i];
        const float4 as = *(const float4*)&asrc[(size_t)s * 4];
        float v0 = as.x + ad.x, v1 = as.y + ad.y, v2 = as.z + ad.z, v3 = as.w + ad.w;
        v0 = v0 > 0.f ? v0 : NEG_SLOPE * v0;
        v1 = v1 > 0.f ? v1 : NEG_SLOPE * v1;
        v2 = v2 > 0.f ? v2 : NEG_SLOPE * v2;
        v3 = v3 > 0.f ? v3 : NEG_SLOPE * v3;
        const float p0 = __expf(v0), p1 = __expf(v1);
        const float p2 = __expf(v2), p3 = __expf(v3);
        d0 += p0; d1 += p1; d2 += p2; d3 += p3;
        if (i < DEG_CAP){
            *(float4*)&plds[wid][i * 4] = make_float4(p0, p1, p2, p3);
            slds[wid][i] = s << 9;               // byte offset of h row
        }
    }
    for (int off = 32; off >= 1; off >>= 1){
        d0 += __shfl_xor(d0, off, 64); d1 += __shfl_xor(d1, off, 64);
        d2 += __shfl_xor(d2, off, 64); d3 += __shfl_xor(d3, off, 64);
    }

    // ---- phase B: 2-unrolled weighted gather-accumulate ----
    float a0 = 0.f, a1 = 0.f, a2 = 0.f, a3 = 0.f;
    {
        const char* hb = (const char*)h + lane * 8;
        const float* pb = &plds[wid][0];
        const int* sb = &slds[wid][0];
#define EDGE_BODY(slot)                                                        \
        {                                                                      \
            const float p_ = pb[(slot) * 4 + head];                            \
            const ushort4 hv_ = *(const ushort4*)(hb + sb[slot]);              \
            a0 = fmaf(p_, bf2f(hv_.x), a0); a1 = fmaf(p_, bf2f(hv_.y), a1);    \
            a2 = fmaf(p_, bf2f(hv_.z), a2); a3 = fmaf(p_, bf2f(hv_.w), a3);    \
        }
        int i = 0;
        for (; i + 2 <= degc; i += 2){
            EDGE_BODY(i);
            EDGE_BODY(i + 1);
        }
        for (; i < degc; ++i) EDGE_BODY(i);
#undef EDGE_BODY
    }

    // overflow path (deg > DEG_CAP): statistically never
    for (int jj = beg + DEG_CAP; jj < end; ++jj){
        const int s = csr[jj];
        const float4 as = *(const float4*)&asrc[(size_t)s * 4];
        float e0 = as.x + ad.x, e1 = as.y + ad.y, e2 = as.z + ad.z, e3 = as.w + ad.w;
        float eh = (head == 0) ? e0 : (head == 1) ? e1 : (head == 2) ? e2 : e3;
        eh = eh > 0.f ? eh : NEG_SLOPE * eh;
        const float p = __expf(eh);
        const ushort4 hv = *(const ushort4*)&h[(size_t)s * 256 + lane * 4];
        a0 = fmaf(p, bf2f(hv.x), a0); a1 = fmaf(p, bf2f(hv.y), a1);
        a2 = fmaf(p, bf2f(hv.z), a2); a3 = fmaf(p, bf2f(hv.w), a3);
    }

    // ---- fused epilogue ----
    const int l15 = lane & 15;
    const float dsel = (head == 0) ? d0 : (head == 1) ? d1 : (head == 2) ? d2 : d3;
    const float rdi = 1.f / dsel;
    const int c0 = head * 64 + 4 * l15;
    const float4 bv  = *(const float4*)&b[c0];
    const float4 gv  = *(const float4*)&g[c0];
    const float4 bev = *(const float4*)&be[c0];
    const float4 mv  = *(const float4*)&mean[c0];
    const float4 vv4 = *(const float4*)&var[c0];
    const float ava[4]  = {a0, a1, a2, a3};
    const float bva[4]  = {bv.x, bv.y, bv.z, bv.w};
    const float gva[4]  = {gv.x, gv.y, gv.z, gv.w};
    const float beva[4] = {bev.x, bev.y, bev.z, bev.w};
    const float mva[4]  = {mv.x, mv.y, mv.z, mv.w};
    const float vva[4]  = {vv4.x, vv4.y, vv4.z, vv4.w};
    float rh[4] = {0.f, 0.f, 0.f, 0.f};
    if (LAST){
        const ushort4 rv = *(const ushort4*)&res[(size_t)node * 256 + c0];
        rh[0] = bf2f(rv.x); rh[1] = bf2f(rv.y); rh[2] = bf2f(rv.z); rh[3] = bf2f(rv.w);
    }
    float vvv[4];
#pragma unroll
    for (int j = 0; j < 4; ++j){
        float v = ava[j] * rdi + bva[j];
        v = (v - mva[j]) * (gva[j] * rsqrtf(vva[j] + BN_EPS)) + beva[j];
        v = v > 0.f ? v : (__expf(v) - 1.f);
        vvv[j] = v + rh[j];
    }
    if (!LAST){
        ushort4 o4;
        o4.x = f2bf(vvv[0]); o4.y = f2bf(vvv[1]);
        o4.z = f2bf(vvv[2]); o4.w = f2bf(vvv[3]);
        *(ushort4*)&outbf[(size_t)node * 256 + c0] = o4;
    } else {
        const float4 w2v = *(const float4*)&W2[c0];
        float part = vvv[0] * w2v.x + vvv[1] * w2v.y + vvv[2] * w2v.z + vvv[3] * w2v.w;
        for (int off = 32; off >= 1; off >>= 1) part += __shfl_xor(part, off, 64);
        if (lane == 0) outh2[node] = part;        // h2[node]
    }
}

// ------------------------- layer 2 aggregate (heads=1, C=1) -------------------------
__global__ void agg2_kernel(const int* __restrict__ row, const int* __restrict__ csr,
                            const float* __restrict__ h2,
                            const float* __restrict__ as2, const float* __restrict__ ad2,
                            const float* __restrict__ b2, float* __restrict__ out, int N)
{
    const int n = blockIdx.x * blockDim.x + threadIdx.x;
    if (n >= N) return;
    const float A_s = as2[0];
    const float hd  = h2[n] * ad2[0];
    const int beg = row[n], end = row[n + 1];
    float den = 0.f, acc = 0.f;
    for (int i = beg; i < end; ++i){
        const float hv = h2[csr[i]];
        float a = fmaf(A_s, hv, hd);
        a = a > 0.f ? a : NEG_SLOPE * a;
        const float p = __expf(a);
        den += p; acc = fmaf(p, hv, acc);
    }
    out[n] = acc / den + b2[0];
}

// =========================================================================
extern "C" void kernel_launch(void* const* d_in, const int* in_sizes, int n_in,
                              void* d_out, int out_size, void* d_ws, size_t ws_size,
                              hipStream_t stream)
{
    const float* x   = (const float*)d_in[0];
    const int*   ei  = (const int*)  d_in[1];
    const float* W0  = (const float*)d_in[2];
    const float* as0 = (const float*)d_in[3];
    const float* ad0 = (const float*)d_in[4];
    const float* b0  = (const float*)d_in[5];
    const float* W1  = (const float*)d_in[6];
    const float* as1 = (const float*)d_in[7];
    const float* ad1 = (const float*)d_in[8];
    const float* b1  = (const float*)d_in[9];
    const float* W2  = (const float*)d_in[10];
    const float* as2 = (const float*)d_in[11];
    const float* ad2 = (const float*)d_in[12];
    const float* b2  = (const float*)d_in[13];
    const float* g0  = (const float*)d_in[14];
    const float* be0 = (const float*)d_in[15];
    const float* m0  = (const float*)d_in[16];
    const float* v0  = (const float*)d_in[17];
    const float* g1  = (const float*)d_in[18];
    const float* be1 = (const float*)d_in[19];
    const float* m1  = (const float*)d_in[20];
    const float* v1  = (const float*)d_in[21];

    const int N = in_sizes[0] / 128;
    const int E = in_sizes[1] / 2;
    const int EN = E + N;

    // ---- workspace layout ----
    char* w = (char*)d_ws;
    unsigned short* H    = (unsigned short*)w;  w += (size_t)N * 256 * 2;  // h bf16 [N][256]
    unsigned short* P0   = (unsigned short*)w;  w += (size_t)N * 256 * 2;  // layer0 out bf16
    float*    asrc   = (float*)w;   w += (size_t)N * 4 * 4;
    float*    adst   = (float*)w;   w += (size_t)N * 4 * 4;
    int*      deg    = (int*)w;     w += (size_t)N * 4;
    int*      cursor = (int*)w;     w += (size_t)N * 4;
    int*      csr    = (int*)w;     w += (size_t)EN * 4;
    float*    h2     = (float*)w;   w += (size_t)N * 4;
    int*      bsum   = (int*)w;     w += 1024;
    unsigned short* Wb0hi = (unsigned short*)w; w += (size_t)128 * 256 * 2;
    unsigned short* Wb0lo = (unsigned short*)w; w += (size_t)128 * 256 * 2;
    unsigned short* Wb1hi = (unsigned short*)w; w += (size_t)256 * 256 * 2;
    unsigned short* Wb1lo = (unsigned short*)w; w += (size_t)256 * 256 * 2;
    int*      rowp   = (int*)w;     w += (size_t)(N + 1) * 4;   // last (odd size)

    const int gN64  = (N + 63) / 64;
    const int gN4   = (N + 3) / 4;
    const int gNt   = (N + 255) / 256;
    const int gE    = (E + 255) / 256;
    const int gEN   = (EN + 255) / 256;
    const int nb    = (N + 1023) / 1024;

    // ---------------- one-time prep: W repack + deg_init (fused), CSR ----------------
    prep_kernel<<<384 + gNt, 256, 0, stream>>>(W0, Wb0hi, Wb0lo, W1, Wb1hi, Wb1lo, deg, N);
    deg_hist_kernel<<<gE, 256, 0, stream>>>(ei, E, deg);
    part_sum_kernel<<<nb, 256, 0, stream>>>(deg, bsum, N);
    scan_part_kernel<<<1, 256, 0, stream>>>(bsum, nb, rowp, N);
    distribute_kernel<<<nb, 256, 0, stream>>>(deg, bsum, rowp, cursor, N);
    scatter_kernel<<<gEN, 256, 0, stream>>>(ei, E, N, cursor, csr);

    // ---------------- layer 0 ----------------
    mfma_gemm0<<<gN64, 256, 0, stream>>>(x, Wb0hi, Wb0lo,
                                         as0, ad0, H, asrc, adst, N);
    agg4_kernel<false><<<gN4, 256, 0, stream>>>(rowp, csr, asrc, adst, H,
                                                b0, g0, be0, m0, v0,
                                                nullptr, P0, nullptr, nullptr, N);

    // ---------------- layer 1 (+ fused h2 = P1 . W2) ----------------
    mfma_gemm1<<<gN64, 256, 0, stream>>>(P0, Wb1hi, Wb1lo,
                                         as1, ad1, H, asrc, adst, N);
    agg4_kernel<true><<<gN4, 256, 0, stream>>>(rowp, csr, asrc, adst, H,
                                               b1, g1, be1, m1, v1,
                                               P0, nullptr, h2, W2, N);

    // ---------------- layer 2 ----------------
    agg2_kernel<<<gNt, 256, 0, stream>>>(rowp, csr, h2, as2, ad2, b2, (float*)d_out, N);
}

// Round 13
// 306.048 us; speedup vs baseline: 1.0610x; 1.0610x over previous
//
#include <hip/hip_runtime.h>
#include <math.h>

#define NEG_SLOPE 0.2f
#define BN_EPS 1e-5f

typedef __attribute__((ext_vector_type(8))) short bf16x8;
typedef __attribute__((ext_vector_type(4))) float f32x4;

static __device__ __forceinline__ unsigned short f2bf(float f){
    unsigned u = __float_as_uint(f);
    u += 0x7FFFu + ((u >> 16) & 1u);          // round-to-nearest-even
    return (unsigned short)(u >> 16);
}
static __device__ __forceinline__ float bf2f(unsigned short v){
    return __uint_as_float((unsigned)v << 16);
}

// async global->LDS, 16B/lane; LDS dest wave-uniform base + lane*16
static __device__ __forceinline__ void gload_lds16(const void* g, void* l){
    __builtin_amdgcn_global_load_lds(
        (const __attribute__((address_space(1))) void*)g,
        (__attribute__((address_space(3))) void*)l, 16, 0, 0);
}

// ---- fused prep: repack W0, W1 to MFMA B-frag hi/lo planes + deg_init ----
static __device__ __forceinline__ void repack_one(const float* __restrict__ W,
    unsigned short* __restrict__ whi, unsigned short* __restrict__ wlo, int o)
{
    const int j = o & 7, ln = (o >> 3) & 63, ct = (o >> 9) & 15, kt = o >> 13;
    const int k = kt * 32 + 8 * (ln >> 4) + j;
    const int col = ct * 16 + (ln & 15);
    const float v = W[k * 256 + col];
    const unsigned short hb = f2bf(v);
    whi[o] = hb; wlo[o] = f2bf(v - bf2f(hb));
}

__global__ void prep_kernel(const float* __restrict__ W0,
    unsigned short* __restrict__ w0hi, unsigned short* __restrict__ w0lo,
    const float* __restrict__ W1,
    unsigned short* __restrict__ w1hi, unsigned short* __restrict__ w1lo,
    int* __restrict__ deg, int N)
{
    const int bid = blockIdx.x, t = threadIdx.x;
    if (bid < 128){
        repack_one(W0, w0hi, w0lo, bid * 256 + t);
    } else if (bid < 384){
        repack_one(W1, w1hi, w1lo, (bid - 128) * 256 + t);
    } else {
        const int i = (bid - 384) * 256 + t;
        if (i < N) deg[i] = 1;                // self-loop
    }
}

// =========================================================================
// HYBRID MFMA GEMMs: A staged via LDS (shared across the 4 waves, coalesced
// global_load_lds); B fully registerized (wave = head; wave-private
// contiguous 16B/lane loads from packed layout -> no LDS, no extra sync).
// gemm0: A = x fp32, hi-plane only in-register (h is bf16-rounded at store;
// W hi/lo kept). C/D map (verified): col=lane&15, row=(lane>>4)*4+reg.
// =========================================================================
__global__ __launch_bounds__(256) void mfma_gemm0(
    const float* __restrict__ x,
    const unsigned short* __restrict__ wbhi, const unsigned short* __restrict__ wblo,
    const float* __restrict__ a_s, const float* __restrict__ a_d,
    unsigned short* __restrict__ hout,
    float* __restrict__ asrc, float* __restrict__ adst, int N)
{
    constexpr int K = 128;
    __shared__ float xaf[4][2][64][4];        // 8KB A-tile (fp32)
    const int t = threadIdx.x, lane = t & 63, wid = t >> 6;
    const int n0 = blockIdx.x * 64;
    const int l15 = lane & 15, lg = lane >> 4;

    const unsigned short* bph = &wbhi[((size_t)(wid * 4) * 64 + lane) * 8];
    const unsigned short* bpl = &wblo[((size_t)(wid * 4) * 64 + lane) * 8];

    f32x4 acc[4][4];
#pragma unroll
    for (int rt = 0; rt < 4; ++rt)
#pragma unroll
        for (int q = 0; q < 4; ++q) acc[rt][q] = (f32x4){0.f, 0.f, 0.f, 0.f};

    for (int kt = 0; kt < K / 32; ++kt){
        __syncthreads();                      // previous iteration LDS reads done
        // stage A (fp32): 8 x 1KB issues, wave wid issues 2
#pragma unroll
        for (int ii = 0; ii < 2; ++ii){
            const int i = wid * 2 + ii;
            const int rt = i >> 1, half = i & 1;
            int node = n0 + rt * 16 + l15;
            if (node > N - 1) node = N - 1;   // clamp; results discarded later
            const float* src = &x[(size_t)node * K + kt * 32 + 8 * lg + half * 4];
            gload_lds16(src, &xaf[rt][half][0][0]);
        }
        // B: wave-private contiguous registers (both planes)
        bf16x8 bhi[4], blo[4];
#pragma unroll
        for (int q = 0; q < 4; ++q){
            bhi[q] = *(const bf16x8*)(bph + ((size_t)kt * 16 + q) * 512);
            blo[q] = *(const bf16x8*)(bpl + ((size_t)kt * 16 + q) * 512);
        }
        __syncthreads();                      // drains vmcnt (incl. lds loads)

        bf16x8 ahi[4];
#pragma unroll
        for (int rt = 0; rt < 4; ++rt){
            const float4 f0 = *(const float4*)&xaf[rt][0][lane][0];
            const float4 f1 = *(const float4*)&xaf[rt][1][lane][0];
            const float fv[8] = {f0.x, f0.y, f0.z, f0.w, f1.x, f1.y, f1.z, f1.w};
#pragma unroll
            for (int j = 0; j < 8; ++j) ahi[rt][j] = (short)f2bf(fv[j]);
        }
#pragma unroll
        for (int q = 0; q < 4; ++q)
#pragma unroll
            for (int rt = 0; rt < 4; ++rt){
                acc[rt][q] = __builtin_amdgcn_mfma_f32_16x16x32_bf16(ahi[rt], bhi[q], acc[rt][q], 0, 0, 0);
                acc[rt][q] = __builtin_amdgcn_mfma_f32_16x16x32_bf16(ahi[rt], blo[q], acc[rt][q], 0, 0, 0);
            }
    }

    // ---- epilogue: h store + alpha reductions ----
    float avs[4], avd[4];
#pragma unroll
    for (int q = 0; q < 4; ++q){
        avs[q] = a_s[wid * 64 + q * 16 + l15];
        avd[q] = a_d[wid * 64 + q * 16 + l15];
    }
    float sp[4][4], dp[4][4];
#pragma unroll
    for (int rt = 0; rt < 4; ++rt){
#pragma unroll
        for (int reg = 0; reg < 4; ++reg){
            const int node = n0 + rt * 16 + lg * 4 + reg;
            float s = 0.f, d = 0.f;
            unsigned short hv[4];
#pragma unroll
            for (int q = 0; q < 4; ++q){
                const float v = acc[rt][q][reg];
                s = fmaf(v, avs[q], s); d = fmaf(v, avd[q], d);
                hv[q] = f2bf(v);
            }
            if (node < N){
#pragma unroll
                for (int q = 0; q < 4; ++q)
                    hout[(size_t)node * 256 + (wid * 4 + q) * 16 + l15] = hv[q];
            }
            sp[rt][reg] = s; dp[rt][reg] = d;
        }
    }
#pragma unroll
    for (int off = 1; off <= 8; off <<= 1){
#pragma unroll
        for (int rt = 0; rt < 4; ++rt)
#pragma unroll
            for (int reg = 0; reg < 4; ++reg){
                sp[rt][reg] += __shfl_xor(sp[rt][reg], off, 64);
                dp[rt][reg] += __shfl_xor(dp[rt][reg], off, 64);
            }
    }
    if (l15 == 0){
#pragma unroll
        for (int rt = 0; rt < 4; ++rt)
#pragma unroll
            for (int reg = 0; reg < 4; ++reg){
                const int node = n0 + rt * 16 + lg * 4 + reg;
                if (node < N){
                    asrc[(size_t)node * 4 + wid] = sp[rt][reg];
                    adst[(size_t)node * 4 + wid] = dp[rt][reg];
                }
            }
    }
}

__global__ __launch_bounds__(256) void mfma_gemm1(
    const unsigned short* __restrict__ xb,
    const unsigned short* __restrict__ wbhi, const unsigned short* __restrict__ wblo,
    const float* __restrict__ a_s, const float* __restrict__ a_d,
    unsigned short* __restrict__ hout,
    float* __restrict__ asrc, float* __restrict__ adst, int N)
{
    constexpr int K = 256;
    __shared__ unsigned short xab[4][512];    // 4KB A-tile (bf16)
    const int t = threadIdx.x, lane = t & 63, wid = t >> 6;
    const int n0 = blockIdx.x * 64;
    const int l15 = lane & 15, lg = lane >> 4;

    const unsigned short* bph = &wbhi[((size_t)(wid * 4) * 64 + lane) * 8];
    const unsigned short* bpl = &wblo[((size_t)(wid * 4) * 64 + lane) * 8];

    f32x4 acc[4][4];
#pragma unroll
    for (int rt = 0; rt < 4; ++rt)
#pragma unroll
        for (int q = 0; q < 4; ++q) acc[rt][q] = (f32x4){0.f, 0.f, 0.f, 0.f};

    for (int kt = 0; kt < K / 32; ++kt){
        __syncthreads();                      // previous iteration LDS reads done
        {   // stage A: wave wid stages rt = wid (1KB)
            const int rt = wid;
            int node = n0 + rt * 16 + l15;
            if (node > N - 1) node = N - 1;
            const unsigned short* src = &xb[(size_t)node * K + kt * 32 + 8 * lg];
            gload_lds16(src, &xab[rt][0]);
        }
        // B: wave-private contiguous registers (both planes)
        bf16x8 bhi[4], blo[4];
#pragma unroll
        for (int q = 0; q < 4; ++q){
            bhi[q] = *(const bf16x8*)(bph + ((size_t)kt * 16 + q) * 512);
            blo[q] = *(const bf16x8*)(bpl + ((size_t)kt * 16 + q) * 512);
        }
        __syncthreads();                      // drains vmcnt (incl. lds loads)

        bf16x8 a[4];
#pragma unroll
        for (int rt = 0; rt < 4; ++rt)
            a[rt] = *(const bf16x8*)&xab[rt][lane * 8];

#pragma unroll
        for (int q = 0; q < 4; ++q)
#pragma unroll
            for (int rt = 0; rt < 4; ++rt){
                acc[rt][q] = __builtin_amdgcn_mfma_f32_16x16x32_bf16(a[rt], bhi[q], acc[rt][q], 0, 0, 0);
                acc[rt][q] = __builtin_amdgcn_mfma_f32_16x16x32_bf16(a[rt], blo[q], acc[rt][q], 0, 0, 0);
            }
    }

    // ---- epilogue ----
    float avs[4], avd[4];
#pragma unroll
    for (int q = 0; q < 4; ++q){
        avs[q] = a_s[wid * 64 + q * 16 + l15];
        avd[q] = a_d[wid * 64 + q * 16 + l15];
    }
    float sp[4][4], dp[4][4];
#pragma unroll
    for (int rt = 0; rt < 4; ++rt){
#pragma unroll
        for (int reg = 0; reg < 4; ++reg){
            const int node = n0 + rt * 16 + lg * 4 + reg;
            float s = 0.f, d = 0.f;
            unsigned short hv[4];
#pragma unroll
            for (int q = 0; q < 4; ++q){
                const float v = acc[rt][q][reg];
                s = fmaf(v, avs[q], s); d = fmaf(v, avd[q], d);
                hv[q] = f2bf(v);
            }
            if (node < N){
#pragma unroll
                for (int q = 0; q < 4; ++q)
                    hout[(size_t)node * 256 + (wid * 4 + q) * 16 + l15] = hv[q];
            }
            sp[rt][reg] = s; dp[rt][reg] = d;
        }
    }
#pragma unroll
    for (int off = 1; off <= 8; off <<= 1){
#pragma unroll
        for (int rt = 0; rt < 4; ++rt)
#pragma unroll
            for (int reg = 0; reg < 4; ++reg){
                sp[rt][reg] += __shfl_xor(sp[rt][reg], off, 64);
                dp[rt][reg] += __shfl_xor(dp[rt][reg], off, 64);
            }
    }
    if (l15 == 0){
#pragma unroll
        for (int rt = 0; rt < 4; ++rt)
#pragma unroll
            for (int reg = 0; reg < 4; ++reg){
                const int node = n0 + rt * 16 + lg * 4 + reg;
                if (node < N){
                    asrc[(size_t)node * 4 + wid] = sp[rt][reg];
                    adst[(size_t)node * 4 + wid] = dp[rt][reg];
                }
            }
    }
}

// ============================ CSR build (once) ============================
__global__ void deg_hist_kernel(const int* __restrict__ ei, int E, int* __restrict__ deg){
    int e = blockIdx.x * blockDim.x + threadIdx.x;
    if (e < E) atomicAdd(&deg[ei[E + e]], 1);
}

__global__ __launch_bounds__(256) void part_sum_kernel(const int* __restrict__ deg,
                                                       int* __restrict__ bsum, int N)
{
    __shared__ int red[256];
    const int t = threadIdx.x;
    const int i0 = blockIdx.x * 1024 + t * 4;
    int s = 0;
    if (i0 + 3 < N){
        const int4 v = *(const int4*)&deg[i0];
        s = v.x + v.y + v.z + v.w;
    } else {
#pragma unroll
        for (int j = 0; j < 4; ++j) if (i0 + j < N) s += deg[i0 + j];
    }
    red[t] = s; __syncthreads();
    for (int off = 128; off >= 1; off >>= 1){
        if (t < off) red[t] += red[t + off];
        __syncthreads();
    }
    if (t == 0) bsum[blockIdx.x] = red[0];
}

__global__ __launch_bounds__(256) void scan_part_kernel(int* __restrict__ bsum, int nb,
                                                        int* __restrict__ row, int N)
{
    __shared__ int sh[256];
    const int t = threadIdx.x;
    const int v = (t < nb) ? bsum[t] : 0;
    sh[t] = v; __syncthreads();
    for (int off = 1; off < 256; off <<= 1){
        int u = (t >= off) ? sh[t - off] : 0;
        __syncthreads();
        sh[t] += u;
        __syncthreads();
    }
    if (t < nb) bsum[t] = sh[t] - v;              // exclusive
    if (t == nb - 1) row[N] = sh[t];              // total = E + N
}

__global__ __launch_bounds__(256) void distribute_kernel(const int* __restrict__ deg,
    const int* __restrict__ bsum, int* __restrict__ row, int* __restrict__ cursor, int N)
{
    __shared__ int ts[256];
    const int t = threadIdx.x;
    const int i0 = blockIdx.x * 1024 + t * 4;
    int d[4]; int s = 0;
#pragma unroll
    for (int j = 0; j < 4; ++j){ d[j] = (i0 + j < N) ? deg[i0 + j] : 0; s += d[j]; }
    ts[t] = s; __syncthreads();
    for (int off = 1; off < 256; off <<= 1){
        int u = (t >= off) ? ts[t - off] : 0;
        __syncthreads();
        ts[t] += u;
        __syncthreads();
    }
    int base = bsum[blockIdx.x] + ts[t] - s;
#pragma unroll
    for (int j = 0; j < 4; ++j){
        if (i0 + j < N){ row[i0 + j] = base; cursor[i0 + j] = base; base += d[j]; }
    }
}

__global__ void scatter_kernel(const int* __restrict__ ei, int E, int N,
                               int* __restrict__ cursor, int* __restrict__ csr)
{
    int e = blockIdx.x * blockDim.x + threadIdx.x;
    if (e >= E + N) return;
    int s, d;
    if (e < E){ s = ei[e]; d = ei[E + e]; } else { s = d = e - E; }
    int pos = atomicAdd(&cursor[d], 1);
    csr[pos] = s;
}

// =========================================================================
// Gather-aggregate: one wave per node, 4 waves/block. h [node][256] bf16;
// lane owns (head = lane>>4, channels 4*lane..4*lane+3).
// Phase A: lane-parallel p=exp(leakyrelu(e)) -> LDS + denom butterfly.
// Phase B: 2-unrolled gather via byte offsets (VGPR-lean, 70% occ).
//   LAST=false: write P0 bf16. LAST=true: +res, h2 = P1.W2 -> outh2[node].
// =========================================================================
#define DEG_CAP 128
template<bool LAST>
__global__ __launch_bounds__(256) void agg4_kernel(
    const int* __restrict__ row, const int* __restrict__ csr,
    const float* __restrict__ asrc, const float* __restrict__ adst,
    const unsigned short* __restrict__ h,
    const float* __restrict__ b, const float* __restrict__ g,
    const float* __restrict__ be, const float* __restrict__ mean,
    const float* __restrict__ var,
    const unsigned short* __restrict__ res,   // bf16 residual (LAST only)
    unsigned short* __restrict__ outbf,       // P0 bf16 (layer0)
    float* __restrict__ outh2,                // h2 (LAST)
    const float* __restrict__ W2,             // LAST only
    int N)
{
    __shared__ float plds[4][DEG_CAP * 4];
    __shared__ int   slds[4][DEG_CAP];
    const int wid = threadIdx.x >> 6, lane = threadIdx.x & 63;
    const int node = blockIdx.x * 4 + wid;
    if (node >= N) return;
    const int beg = row[node], end = row[node + 1], deg = end - beg;
    const int degc = deg < DEG_CAP ? deg : DEG_CAP;
    const int head = lane >> 4;

    const float4 ad = *(const float4*)&adst[(size_t)node * 4];

    // ---- phase A ----
    float d0 = 0.f, d1 = 0.f, d2 = 0.f, d3 = 0.f;
    for (int i = lane; i < deg; i += 64){
        const int s = csr[beg + i];
        const float4 as = *(const float4*)&asrc[(size_t)s * 4];
        float v0 = as.x + ad.x, v1 = as.y + ad.y, v2 = as.z + ad.z, v3 = as.w + ad.w;
        v0 = v0 > 0.f ? v0 : NEG_SLOPE * v0;
        v1 = v1 > 0.f ? v1 : NEG_SLOPE * v1;
        v2 = v2 > 0.f ? v2 : NEG_SLOPE * v2;
        v3 = v3 > 0.f ? v3 : NEG_SLOPE * v3;
        const float p0 = __expf(v0), p1 = __expf(v1);
        const float p2 = __expf(v2), p3 = __expf(v3);
        d0 += p0; d1 += p1; d2 += p2; d3 += p3;
        if (i < DEG_CAP){
            *(float4*)&plds[wid][i * 4] = make_float4(p0, p1, p2, p3);
            slds[wid][i] = s << 9;               // byte offset of h row
        }
    }
    for (int off = 32; off >= 1; off >>= 1){
        d0 += __shfl_xor(d0, off, 64); d1 += __shfl_xor(d1, off, 64);
        d2 += __shfl_xor(d2, off, 64); d3 += __shfl_xor(d3, off, 64);
    }

    // ---- phase B: 2-unrolled weighted gather-accumulate ----
    float a0 = 0.f, a1 = 0.f, a2 = 0.f, a3 = 0.f;
    {
        const char* hb = (const char*)h + lane * 8;
        const float* pb = &plds[wid][0];
        const int* sb = &slds[wid][0];
#define EDGE_BODY(slot)                                                        \
        {                                                                      \
            const float p_ = pb[(slot) * 4 + head];                            \
            const ushort4 hv_ = *(const ushort4*)(hb + sb[slot]);              \
            a0 = fmaf(p_, bf2f(hv_.x), a0); a1 = fmaf(p_, bf2f(hv_.y), a1);    \
            a2 = fmaf(p_, bf2f(hv_.z), a2); a3 = fmaf(p_, bf2f(hv_.w), a3);    \
        }
        int i = 0;
        for (; i + 2 <= degc; i += 2){
            EDGE_BODY(i);
            EDGE_BODY(i + 1);
        }
        for (; i < degc; ++i) EDGE_BODY(i);
#undef EDGE_BODY
    }

    // overflow path (deg > DEG_CAP): statistically never
    for (int jj = beg + DEG_CAP; jj < end; ++jj){
        const int s = csr[jj];
        const float4 as = *(const float4*)&asrc[(size_t)s * 4];
        float e0 = as.x + ad.x, e1 = as.y + ad.y, e2 = as.z + ad.z, e3 = as.w + ad.w;
        float eh = (head == 0) ? e0 : (head == 1) ? e1 : (head == 2) ? e2 : e3;
        eh = eh > 0.f ? eh : NEG_SLOPE * eh;
        const float p = __expf(eh);
        const ushort4 hv = *(const ushort4*)&h[(size_t)s * 256 + lane * 4];
        a0 = fmaf(p, bf2f(hv.x), a0); a1 = fmaf(p, bf2f(hv.y), a1);
        a2 = fmaf(p, bf2f(hv.z), a2); a3 = fmaf(p, bf2f(hv.w), a3);
    }

    // ---- fused epilogue ----
    const int l15 = lane & 15;
    const float dsel = (head == 0) ? d0 : (head == 1) ? d1 : (head == 2) ? d2 : d3;
    const float rdi = 1.f / dsel;
    const int c0 = head * 64 + 4 * l15;
    const float4 bv  = *(const float4*)&b[c0];
    const float4 gv  = *(const float4*)&g[c0];
    const float4 bev = *(const float4*)&be[c0];
    const float4 mv  = *(const float4*)&mean[c0];
    const float4 vv4 = *(const float4*)&var[c0];
    const float ava[4]  = {a0, a1, a2, a3};
    const float bva[4]  = {bv.x, bv.y, bv.z, bv.w};
    const float gva[4]  = {gv.x, gv.y, gv.z, gv.w};
    const float beva[4] = {bev.x, bev.y, bev.z, bev.w};
    const float mva[4]  = {mv.x, mv.y, mv.z, mv.w};
    const float vva[4]  = {vv4.x, vv4.y, vv4.z, vv4.w};
    float rh[4] = {0.f, 0.f, 0.f, 0.f};
    if (LAST){
        const ushort4 rv = *(const ushort4*)&res[(size_t)node * 256 + c0];
        rh[0] = bf2f(rv.x); rh[1] = bf2f(rv.y); rh[2] = bf2f(rv.z); rh[3] = bf2f(rv.w);
    }
    float vvv[4];
#pragma unroll
    for (int j = 0; j < 4; ++j){
        float v = ava[j] * rdi + bva[j];
        v = (v - mva[j]) * (gva[j] * rsqrtf(vva[j] + BN_EPS)) + beva[j];
        v = v > 0.f ? v : (__expf(v) - 1.f);
        vvv[j] = v + rh[j];
    }
    if (!LAST){
        ushort4 o4;
        o4.x = f2bf(vvv[0]); o4.y = f2bf(vvv[1]);
        o4.z = f2bf(vvv[2]); o4.w = f2bf(vvv[3]);
        *(ushort4*)&outbf[(size_t)node * 256 + c0] = o4;
    } else {
        const float4 w2v = *(const float4*)&W2[c0];
        float part = vvv[0] * w2v.x + vvv[1] * w2v.y + vvv[2] * w2v.z + vvv[3] * w2v.w;
        for (int off = 32; off >= 1; off >>= 1) part += __shfl_xor(part, off, 64);
        if (lane == 0) outh2[node] = part;        // h2[node]
    }
}

// ------------------------- layer 2 aggregate (heads=1, C=1) -------------------------
__global__ void agg2_kernel(const int* __restrict__ row, const int* __restrict__ csr,
                            const float* __restrict__ h2,
                            const float* __restrict__ as2, const float* __restrict__ ad2,
                            const float* __restrict__ b2, float* __restrict__ out, int N)
{
    const int n = blockIdx.x * blockDim.x + threadIdx.x;
    if (n >= N) return;
    const float A_s = as2[0];
    const float hd  = h2[n] * ad2[0];
    const int beg = row[n], end = row[n + 1];
    float den = 0.f, acc = 0.f;
    for (int i = beg; i < end; ++i){
        const float hv = h2[csr[i]];
        float a = fmaf(A_s, hv, hd);
        a = a > 0.f ? a : NEG_SLOPE * a;
        const float p = __expf(a);
        den += p; acc = fmaf(p, hv, acc);
    }
    out[n] = acc / den + b2[0];
}

// =========================================================================
extern "C" void kernel_launch(void* const* d_in, const int* in_sizes, int n_in,
                              void* d_out, int out_size, void* d_ws, size_t ws_size,
                              hipStream_t stream)
{
    const float* x   = (const float*)d_in[0];
    const int*   ei  = (const int*)  d_in[1];
    const float* W0  = (const float*)d_in[2];
    const float* as0 = (const float*)d_in[3];
    const float* ad0 = (const float*)d_in[4];
    const float* b0  = (const float*)d_in[5];
    const float* W1  = (const float*)d_in[6];
    const float* as1 = (const float*)d_in[7];
    const float* ad1 = (const float*)d_in[8];
    const float* b1  = (const float*)d_in[9];
    const float* W2  = (const float*)d_in[10];
    const float* as2 = (const float*)d_in[11];
    const float* ad2 = (const float*)d_in[12];
    const float* b2  = (const float*)d_in[13];
    const float* g0  = (const float*)d_in[14];
    const float* be0 = (const float*)d_in[15];
    const float* m0  = (const float*)d_in[16];
    const float* v0  = (const float*)d_in[17];
    const float* g1  = (const float*)d_in[18];
    const float* be1 = (const float*)d_in[19];
    const float* m1  = (const float*)d_in[20];
    const float* v1  = (const float*)d_in[21];

    const int N = in_sizes[0] / 128;
    const int E = in_sizes[1] / 2;
    const int EN = E + N;

    // ---- workspace layout ----
    char* w = (char*)d_ws;
    unsigned short* H    = (unsigned short*)w;  w += (size_t)N * 256 * 2;  // h bf16 [N][256]
    unsigned short* P0   = (unsigned short*)w;  w += (size_t)N * 256 * 2;  // layer0 out bf16
    float*    asrc   = (float*)w;   w += (size_t)N * 4 * 4;
    float*    adst   = (float*)w;   w += (size_t)N * 4 * 4;
    int*      deg    = (int*)w;     w += (size_t)N * 4;
    int*      cursor = (int*)w;     w += (size_t)N * 4;
    int*      csr    = (int*)w;     w += (size_t)EN * 4;
    float*    h2     = (float*)w;   w += (size_t)N * 4;
    int*      bsum   = (int*)w;     w += 1024;
    unsigned short* Wb0hi = (unsigned short*)w; w += (size_t)128 * 256 * 2;
    unsigned short* Wb0lo = (unsigned short*)w; w += (size_t)128 * 256 * 2;
    unsigned short* Wb1hi = (unsigned short*)w; w += (size_t)256 * 256 * 2;
    unsigned short* Wb1lo = (unsigned short*)w; w += (size_t)256 * 256 * 2;
    int*      rowp   = (int*)w;     w += (size_t)(N + 1) * 4;   // last (odd size)

    const int gN64  = (N + 63) / 64;
    const int gN4   = (N + 3) / 4;
    const int gNt   = (N + 255) / 256;
    const int gE    = (E + 255) / 256;
    const int gEN   = (EN + 255) / 256;
    const int nb    = (N + 1023) / 1024;

    // ---------------- one-time prep: W repack + deg_init (fused), CSR ----------------
    prep_kernel<<<384 + gNt, 256, 0, stream>>>(W0, Wb0hi, Wb0lo, W1, Wb1hi, Wb1lo, deg, N);
    deg_hist_kernel<<<gE, 256, 0, stream>>>(ei, E, deg);
    part_sum_kernel<<<nb, 256, 0, stream>>>(deg, bsum, N);
    scan_part_kernel<<<1, 256, 0, stream>>>(bsum, nb, rowp, N);
    distribute_kernel<<<nb, 256, 0, stream>>>(deg, bsum, rowp, cursor, N);
    scatter_kernel<<<gEN, 256, 0, stream>>>(ei, E, N, cursor, csr);

    // ---------------- layer 0 ----------------
    mfma_gemm0<<<gN64, 256, 0, stream>>>(x, Wb0hi, Wb0lo,
                                         as0, ad0, H, asrc, adst, N);
    agg4_kernel<false><<<gN4, 256, 0, stream>>>(rowp, csr, asrc, adst, H,
                                                b0, g0, be0, m0, v0,
                                                nullptr, P0, nullptr, nullptr, N);

    // ---------------- layer 1 (+ fused h2 = P1 . W2) ----------------
    mfma_gemm1<<<gN64, 256, 0, stream>>>(P0, Wb1hi, Wb1lo,
                                         as1, ad1, H, asrc, adst, N);
    agg4_kernel<true><<<gN4, 256, 0, stream>>>(rowp, csr, asrc, adst, H,
                                               b1, g1, be1, m1, v1,
                                               P0, nullptr, h2, W2, N);

    // ---------------- layer 2 ----------------
    agg2_kernel<<<gNt, 256, 0, stream>>>(rowp, csr, h2, as2, ad2, b2, (float*)d_out, N);
}

// Round 14
// 305.293 us; speedup vs baseline: 1.0637x; 1.0025x over previous
//
#include <hip/hip_runtime.h>
#include <math.h>

#define NEG_SLOPE 0.2f
#define BN_EPS 1e-5f

typedef __attribute__((ext_vector_type(8))) short bf16x8;
typedef __attribute__((ext_vector_type(4))) float f32x4;

static __device__ __forceinline__ unsigned short f2bf(float f){
    unsigned u = __float_as_uint(f);
    u += 0x7FFFu + ((u >> 16) & 1u);          // round-to-nearest-even
    return (unsigned short)(u >> 16);
}
static __device__ __forceinline__ float bf2f(unsigned short v){
    return __uint_as_float((unsigned)v << 16);
}

// async global->LDS, 16B/lane; LDS dest wave-uniform base + lane*16
static __device__ __forceinline__ void gload_lds16(const void* g, void* l){
    __builtin_amdgcn_global_load_lds(
        (const __attribute__((address_space(1))) void*)g,
        (__attribute__((address_space(3))) void*)l, 16, 0, 0);
}

// ---- fused prep: repack W0, W1 to MFMA B-frag hi/lo planes + deg_init ----
static __device__ __forceinline__ void repack_one(const float* __restrict__ W,
    unsigned short* __restrict__ whi, unsigned short* __restrict__ wlo, int o)
{
    const int j = o & 7, ln = (o >> 3) & 63, ct = (o >> 9) & 15, kt = o >> 13;
    const int k = kt * 32 + 8 * (ln >> 4) + j;
    const int col = ct * 16 + (ln & 15);
    const float v = W[k * 256 + col];
    const unsigned short hb = f2bf(v);
    whi[o] = hb; wlo[o] = f2bf(v - bf2f(hb));
}

__global__ void prep_kernel(const float* __restrict__ W0,
    unsigned short* __restrict__ w0hi, unsigned short* __restrict__ w0lo,
    const float* __restrict__ W1,
    unsigned short* __restrict__ w1hi, unsigned short* __restrict__ w1lo,
    int* __restrict__ deg, int N)
{
    const int bid = blockIdx.x, t = threadIdx.x;
    if (bid < 128){
        repack_one(W0, w0hi, w0lo, bid * 256 + t);
    } else if (bid < 384){
        repack_one(W1, w1hi, w1lo, (bid - 128) * 256 + t);
    } else {
        const int i = (bid - 384) * 256 + t;
        if (i < N) deg[i] = 1;                // self-loop
    }
}

// =========================================================================
// MFMA GEMMs, A-PREFETCH-ALL structure: the whole 64-node A-tile (32 KB) is
// staged to LDS in ONE shot (8 global_load_lds per wave), one barrier, then
// a barrier-free kt loop: wave-private B register loads (vmcnt only) + LDS
// A-frag reads + MFMA. No HBM latency on the loop critical path.
// C/D map (verified): col=lane&15, row=(lane>>4)*4+reg. Wave = head.
// =========================================================================
__global__ __launch_bounds__(256) void mfma_gemm0(
    const float* __restrict__ x,
    const unsigned short* __restrict__ wbhi, const unsigned short* __restrict__ wblo,
    const float* __restrict__ a_s, const float* __restrict__ a_d,
    unsigned short* __restrict__ hout,
    float* __restrict__ asrc, float* __restrict__ adst, int N)
{
    constexpr int K = 128;
    __shared__ float xaf[4][4][2][64][4];     // [kt][rt][half][lane][4] = 32KB
    const int t = threadIdx.x, lane = t & 63, wid = t >> 6;
    const int n0 = blockIdx.x * 64;
    const int l15 = lane & 15, lg = lane >> 4;

    // ---- stage ALL A: 32 issues, 8 per wave ----
#pragma unroll
    for (int ii = 0; ii < 8; ++ii){
        const int i = wid * 8 + ii;
        const int kt = i >> 3, rt = (i >> 1) & 3, half = i & 1;
        int node = n0 + rt * 16 + l15;
        if (node > N - 1) node = N - 1;       // clamp; results discarded later
        const float* src = &x[(size_t)node * K + kt * 32 + 8 * lg + half * 4];
        gload_lds16(src, &xaf[kt][rt][half][0][0]);
    }

    const unsigned short* bph = &wbhi[((size_t)(wid * 4) * 64 + lane) * 8];
    const unsigned short* bpl = &wblo[((size_t)(wid * 4) * 64 + lane) * 8];

    f32x4 acc[4][4];
#pragma unroll
    for (int rt = 0; rt < 4; ++rt)
#pragma unroll
        for (int q = 0; q < 4; ++q) acc[rt][q] = (f32x4){0.f, 0.f, 0.f, 0.f};

    __syncthreads();                          // single drain: A-tile resident

#pragma unroll
    for (int kt = 0; kt < K / 32; ++kt){
        bf16x8 bhi[4], blo[4];
#pragma unroll
        for (int q = 0; q < 4; ++q){
            bhi[q] = *(const bf16x8*)(bph + ((size_t)kt * 16 + q) * 512);
            blo[q] = *(const bf16x8*)(bpl + ((size_t)kt * 16 + q) * 512);
        }
        bf16x8 ahi[4];
#pragma unroll
        for (int rt = 0; rt < 4; ++rt){
            const float4 f0 = *(const float4*)&xaf[kt][rt][0][lane][0];
            const float4 f1 = *(const float4*)&xaf[kt][rt][1][lane][0];
            const float fv[8] = {f0.x, f0.y, f0.z, f0.w, f1.x, f1.y, f1.z, f1.w};
#pragma unroll
            for (int j = 0; j < 8; ++j) ahi[rt][j] = (short)f2bf(fv[j]);
        }
#pragma unroll
        for (int q = 0; q < 4; ++q)
#pragma unroll
            for (int rt = 0; rt < 4; ++rt){
                acc[rt][q] = __builtin_amdgcn_mfma_f32_16x16x32_bf16(ahi[rt], bhi[q], acc[rt][q], 0, 0, 0);
                acc[rt][q] = __builtin_amdgcn_mfma_f32_16x16x32_bf16(ahi[rt], blo[q], acc[rt][q], 0, 0, 0);
            }
    }

    // ---- epilogue: h store + alpha reductions ----
    float avs[4], avd[4];
#pragma unroll
    for (int q = 0; q < 4; ++q){
        avs[q] = a_s[wid * 64 + q * 16 + l15];
        avd[q] = a_d[wid * 64 + q * 16 + l15];
    }
    float sp[4][4], dp[4][4];
#pragma unroll
    for (int rt = 0; rt < 4; ++rt){
#pragma unroll
        for (int reg = 0; reg < 4; ++reg){
            const int node = n0 + rt * 16 + lg * 4 + reg;
            float s = 0.f, d = 0.f;
            unsigned short hv[4];
#pragma unroll
            for (int q = 0; q < 4; ++q){
                const float v = acc[rt][q][reg];
                s = fmaf(v, avs[q], s); d = fmaf(v, avd[q], d);
                hv[q] = f2bf(v);
            }
            if (node < N){
#pragma unroll
                for (int q = 0; q < 4; ++q)
                    hout[(size_t)node * 256 + (wid * 4 + q) * 16 + l15] = hv[q];
            }
            sp[rt][reg] = s; dp[rt][reg] = d;
        }
    }
#pragma unroll
    for (int off = 1; off <= 8; off <<= 1){
#pragma unroll
        for (int rt = 0; rt < 4; ++rt)
#pragma unroll
            for (int reg = 0; reg < 4; ++reg){
                sp[rt][reg] += __shfl_xor(sp[rt][reg], off, 64);
                dp[rt][reg] += __shfl_xor(dp[rt][reg], off, 64);
            }
    }
    if (l15 == 0){
#pragma unroll
        for (int rt = 0; rt < 4; ++rt)
#pragma unroll
            for (int reg = 0; reg < 4; ++reg){
                const int node = n0 + rt * 16 + lg * 4 + reg;
                if (node < N){
                    asrc[(size_t)node * 4 + wid] = sp[rt][reg];
                    adst[(size_t)node * 4 + wid] = dp[rt][reg];
                }
            }
    }
}

__global__ __launch_bounds__(256) void mfma_gemm1(
    const unsigned short* __restrict__ xb,
    const unsigned short* __restrict__ wbhi, const unsigned short* __restrict__ wblo,
    const float* __restrict__ a_s, const float* __restrict__ a_d,
    unsigned short* __restrict__ hout,
    float* __restrict__ asrc, float* __restrict__ adst, int N)
{
    constexpr int K = 256;
    __shared__ unsigned short xab[8][4][512]; // [kt][rt][lane*8] = 32KB
    const int t = threadIdx.x, lane = t & 63, wid = t >> 6;
    const int n0 = blockIdx.x * 64;
    const int l15 = lane & 15, lg = lane >> 4;

    // ---- stage ALL A: 32 issues, 8 per wave ----
#pragma unroll
    for (int ii = 0; ii < 8; ++ii){
        const int i = wid * 8 + ii;
        const int kt = i >> 2, rt = i & 3;
        int node = n0 + rt * 16 + l15;
        if (node > N - 1) node = N - 1;
        const unsigned short* src = &xb[(size_t)node * K + kt * 32 + 8 * lg];
        gload_lds16(src, &xab[kt][rt][0]);
    }

    const unsigned short* bph = &wbhi[((size_t)(wid * 4) * 64 + lane) * 8];
    const unsigned short* bpl = &wblo[((size_t)(wid * 4) * 64 + lane) * 8];

    f32x4 acc[4][4];
#pragma unroll
    for (int rt = 0; rt < 4; ++rt)
#pragma unroll
        for (int q = 0; q < 4; ++q) acc[rt][q] = (f32x4){0.f, 0.f, 0.f, 0.f};

    __syncthreads();                          // single drain: A-tile resident

#pragma unroll
    for (int kt = 0; kt < K / 32; ++kt){
        bf16x8 bhi[4], blo[4];
#pragma unroll
        for (int q = 0; q < 4; ++q){
            bhi[q] = *(const bf16x8*)(bph + ((size_t)kt * 16 + q) * 512);
            blo[q] = *(const bf16x8*)(bpl + ((size_t)kt * 16 + q) * 512);
        }
        bf16x8 a[4];
#pragma unroll
        for (int rt = 0; rt < 4; ++rt)
            a[rt] = *(const bf16x8*)&xab[kt][rt][lane * 8];

#pragma unroll
        for (int q = 0; q < 4; ++q)
#pragma unroll
            for (int rt = 0; rt < 4; ++rt){
                acc[rt][q] = __builtin_amdgcn_mfma_f32_16x16x32_bf16(a[rt], bhi[q], acc[rt][q], 0, 0, 0);
                acc[rt][q] = __builtin_amdgcn_mfma_f32_16x16x32_bf16(a[rt], blo[q], acc[rt][q], 0, 0, 0);
            }
    }

    // ---- epilogue ----
    float avs[4], avd[4];
#pragma unroll
    for (int q = 0; q < 4; ++q){
        avs[q] = a_s[wid * 64 + q * 16 + l15];
        avd[q] = a_d[wid * 64 + q * 16 + l15];
    }
    float sp[4][4], dp[4][4];
#pragma unroll
    for (int rt = 0; rt < 4; ++rt){
#pragma unroll
        for (int reg = 0; reg < 4; ++reg){
            const int node = n0 + rt * 16 + lg * 4 + reg;
            float s = 0.f, d = 0.f;
            unsigned short hv[4];
#pragma unroll
            for (int q = 0; q < 4; ++q){
                const float v = acc[rt][q][reg];
                s = fmaf(v, avs[q], s); d = fmaf(v, avd[q], d);
                hv[q] = f2bf(v);
            }
            if (node < N){
#pragma unroll
                for (int q = 0; q < 4; ++q)
                    hout[(size_t)node * 256 + (wid * 4 + q) * 16 + l15] = hv[q];
            }
            sp[rt][reg] = s; dp[rt][reg] = d;
        }
    }
#pragma unroll
    for (int off = 1; off <= 8; off <<= 1){
#pragma unroll
        for (int rt = 0; rt < 4; ++rt)
#pragma unroll
            for (int reg = 0; reg < 4; ++reg){
                sp[rt][reg] += __shfl_xor(sp[rt][reg], off, 64);
                dp[rt][reg] += __shfl_xor(dp[rt][reg], off, 64);
            }
    }
    if (l15 == 0){
#pragma unroll
        for (int rt = 0; rt < 4; ++rt)
#pragma unroll
            for (int reg = 0; reg < 4; ++reg){
                const int node = n0 + rt * 16 + lg * 4 + reg;
                if (node < N){
                    asrc[(size_t)node * 4 + wid] = sp[rt][reg];
                    adst[(size_t)node * 4 + wid] = dp[rt][reg];
                }
            }
    }
}

// ============================ CSR build (once) ============================
__global__ void deg_hist_kernel(const int* __restrict__ ei, int E, int* __restrict__ deg){
    int e = blockIdx.x * blockDim.x + threadIdx.x;
    if (e < E) atomicAdd(&deg[ei[E + e]], 1);
}

__global__ __launch_bounds__(256) void part_sum_kernel(const int* __restrict__ deg,
                                                       int* __restrict__ bsum, int N)
{
    __shared__ int red[256];
    const int t = threadIdx.x;
    const int i0 = blockIdx.x * 1024 + t * 4;
    int s = 0;
    if (i0 + 3 < N){
        const int4 v = *(const int4*)&deg[i0];
        s = v.x + v.y + v.z + v.w;
    } else {
#pragma unroll
        for (int j = 0; j < 4; ++j) if (i0 + j < N) s += deg[i0 + j];
    }
    red[t] = s; __syncthreads();
    for (int off = 128; off >= 1; off >>= 1){
        if (t < off) red[t] += red[t + off];
        __syncthreads();
    }
    if (t == 0) bsum[blockIdx.x] = red[0];
}

__global__ __launch_bounds__(256) void scan_part_kernel(int* __restrict__ bsum, int nb,
                                                        int* __restrict__ row, int N)
{
    __shared__ int sh[256];
    const int t = threadIdx.x;
    const int v = (t < nb) ? bsum[t] : 0;
    sh[t] = v; __syncthreads();
    for (int off = 1; off < 256; off <<= 1){
        int u = (t >= off) ? sh[t - off] : 0;
        __syncthreads();
        sh[t] += u;
        __syncthreads();
    }
    if (t < nb) bsum[t] = sh[t] - v;              // exclusive
    if (t == nb - 1) row[N] = sh[t];              // total = E + N
}

__global__ __launch_bounds__(256) void distribute_kernel(const int* __restrict__ deg,
    const int* __restrict__ bsum, int* __restrict__ row, int* __restrict__ cursor, int N)
{
    __shared__ int ts[256];
    const int t = threadIdx.x;
    const int i0 = blockIdx.x * 1024 + t * 4;
    int d[4]; int s = 0;
#pragma unroll
    for (int j = 0; j < 4; ++j){ d[j] = (i0 + j < N) ? deg[i0 + j] : 0; s += d[j]; }
    ts[t] = s; __syncthreads();
    for (int off = 1; off < 256; off <<= 1){
        int u = (t >= off) ? ts[t - off] : 0;
        __syncthreads();
        ts[t] += u;
        __syncthreads();
    }
    int base = bsum[blockIdx.x] + ts[t] - s;
#pragma unroll
    for (int j = 0; j < 4; ++j){
        if (i0 + j < N){ row[i0 + j] = base; cursor[i0 + j] = base; base += d[j]; }
    }
}

__global__ void scatter_kernel(const int* __restrict__ ei, int E, int N,
                               int* __restrict__ cursor, int* __restrict__ csr)
{
    int e = blockIdx.x * blockDim.x + threadIdx.x;
    if (e >= E + N) return;
    int s, d;
    if (e < E){ s = ei[e]; d = ei[E + e]; } else { s = d = e - E; }
    int pos = atomicAdd(&cursor[d], 1);
    csr[pos] = s;
}

// =========================================================================
// Gather-aggregate: one wave per node, 4 waves/block. h [node][256] bf16;
// lane owns (head = lane>>4, channels 4*lane..4*lane+3).
// Phase A: lane-parallel p=exp(leakyrelu(e)) -> LDS + denom butterfly.
// Phase B: 2-unrolled gather via byte offsets (VGPR-lean, 70% occ).
//   LAST=false: write P0 bf16. LAST=true: +res, h2 = P1.W2 -> outh2[node].
// =========================================================================
#define DEG_CAP 128
template<bool LAST>
__global__ __launch_bounds__(256) void agg4_kernel(
    const int* __restrict__ row, const int* __restrict__ csr,
    const float* __restrict__ asrc, const float* __restrict__ adst,
    const unsigned short* __restrict__ h,
    const float* __restrict__ b, const float* __restrict__ g,
    const float* __restrict__ be, const float* __restrict__ mean,
    const float* __restrict__ var,
    const unsigned short* __restrict__ res,   // bf16 residual (LAST only)
    unsigned short* __restrict__ outbf,       // P0 bf16 (layer0)
    float* __restrict__ outh2,                // h2 (LAST)
    const float* __restrict__ W2,             // LAST only
    int N)
{
    __shared__ float plds[4][DEG_CAP * 4];
    __shared__ int   slds[4][DEG_CAP];
    const int wid = threadIdx.x >> 6, lane = threadIdx.x & 63;
    const int node = blockIdx.x * 4 + wid;
    if (node >= N) return;
    const int beg = row[node], end = row[node + 1], deg = end - beg;
    const int degc = deg < DEG_CAP ? deg : DEG_CAP;
    const int head = lane >> 4;

    const float4 ad = *(const float4*)&adst[(size_t)node * 4];

    // ---- phase A ----
    float d0 = 0.f, d1 = 0.f, d2 = 0.f, d3 = 0.f;
    for (int i = lane; i < deg; i += 64){
        const int s = csr[beg + i];
        const float4 as = *(const float4*)&asrc[(size_t)s * 4];
        float v0 = as.x + ad.x, v1 = as.y + ad.y, v2 = as.z + ad.z, v3 = as.w + ad.w;
        v0 = v0 > 0.f ? v0 : NEG_SLOPE * v0;
        v1 = v1 > 0.f ? v1 : NEG_SLOPE * v1;
        v2 = v2 > 0.f ? v2 : NEG_SLOPE * v2;
        v3 = v3 > 0.f ? v3 : NEG_SLOPE * v3;
        const float p0 = __expf(v0), p1 = __expf(v1);
        const float p2 = __expf(v2), p3 = __expf(v3);
        d0 += p0; d1 += p1; d2 += p2; d3 += p3;
        if (i < DEG_CAP){
            *(float4*)&plds[wid][i * 4] = make_float4(p0, p1, p2, p3);
            slds[wid][i] = s << 9;               // byte offset of h row
        }
    }
    for (int off = 32; off >= 1; off >>= 1){
        d0 += __shfl_xor(d0, off, 64); d1 += __shfl_xor(d1, off, 64);
        d2 += __shfl_xor(d2, off, 64); d3 += __shfl_xor(d3, off, 64);
    }

    // ---- phase B: 2-unrolled weighted gather-accumulate ----
    float a0 = 0.f, a1 = 0.f, a2 = 0.f, a3 = 0.f;
    {
        const char* hb = (const char*)h + lane * 8;
        const float* pb = &plds[wid][0];
        const int* sb = &slds[wid][0];
#define EDGE_BODY(slot)                                                        \
        {                                                                      \
            const float p_ = pb[(slot) * 4 + head];                            \
            const ushort4 hv_ = *(const ushort4*)(hb + sb[slot]);              \
            a0 = fmaf(p_, bf2f(hv_.x), a0); a1 = fmaf(p_, bf2f(hv_.y), a1);    \
            a2 = fmaf(p_, bf2f(hv_.z), a2); a3 = fmaf(p_, bf2f(hv_.w), a3);    \
        }
        int i = 0;
        for (; i + 2 <= degc; i += 2){
            EDGE_BODY(i);
            EDGE_BODY(i + 1);
        }
        for (; i < degc; ++i) EDGE_BODY(i);
#undef EDGE_BODY
    }

    // overflow path (deg > DEG_CAP): statistically never
    for (int jj = beg + DEG_CAP; jj < end; ++jj){
        const int s = csr[jj];
        const float4 as = *(const float4*)&asrc[(size_t)s * 4];
        float e0 = as.x + ad.x, e1 = as.y + ad.y, e2 = as.z + ad.z, e3 = as.w + ad.w;
        float eh = (head == 0) ? e0 : (head == 1) ? e1 : (head == 2) ? e2 : e3;
        eh = eh > 0.f ? eh : NEG_SLOPE * eh;
        const float p = __expf(eh);
        const ushort4 hv = *(const ushort4*)&h[(size_t)s * 256 + lane * 4];
        a0 = fmaf(p, bf2f(hv.x), a0); a1 = fmaf(p, bf2f(hv.y), a1);
        a2 = fmaf(p, bf2f(hv.z), a2); a3 = fmaf(p, bf2f(hv.w), a3);
    }

    // ---- fused epilogue ----
    const int l15 = lane & 15;
    const float dsel = (head == 0) ? d0 : (head == 1) ? d1 : (head == 2) ? d2 : d3;
    const float rdi = 1.f / dsel;
    const int c0 = head * 64 + 4 * l15;
    const float4 bv  = *(const float4*)&b[c0];
    const float4 gv  = *(const float4*)&g[c0];
    const float4 bev = *(const float4*)&be[c0];
    const float4 mv  = *(const float4*)&mean[c0];
    const float4 vv4 = *(const float4*)&var[c0];
    const float ava[4]  = {a0, a1, a2, a3};
    const float bva[4]  = {bv.x, bv.y, bv.z, bv.w};
    const float gva[4]  = {gv.x, gv.y, gv.z, gv.w};
    const float beva[4] = {bev.x, bev.y, bev.z, bev.w};
    const float mva[4]  = {mv.x, mv.y, mv.z, mv.w};
    const float vva[4]  = {vv4.x, vv4.y, vv4.z, vv4.w};
    float rh[4] = {0.f, 0.f, 0.f, 0.f};
    if (LAST){
        const ushort4 rv = *(const ushort4*)&res[(size_t)node * 256 + c0];
        rh[0] = bf2f(rv.x); rh[1] = bf2f(rv.y); rh[2] = bf2f(rv.z); rh[3] = bf2f(rv.w);
    }
    float vvv[4];
#pragma unroll
    for (int j = 0; j < 4; ++j){
        float v = ava[j] * rdi + bva[j];
        v = (v - mva[j]) * (gva[j] * rsqrtf(vva[j] + BN_EPS)) + beva[j];
        v = v > 0.f ? v : (__expf(v) - 1.f);
        vvv[j] = v + rh[j];
    }
    if (!LAST){
        ushort4 o4;
        o4.x = f2bf(vvv[0]); o4.y = f2bf(vvv[1]);
        o4.z = f2bf(vvv[2]); o4.w = f2bf(vvv[3]);
        *(ushort4*)&outbf[(size_t)node * 256 + c0] = o4;
    } else {
        const float4 w2v = *(const float4*)&W2[c0];
        float part = vvv[0] * w2v.x + vvv[1] * w2v.y + vvv[2] * w2v.z + vvv[3] * w2v.w;
        for (int off = 32; off >= 1; off >>= 1) part += __shfl_xor(part, off, 64);
        if (lane == 0) outh2[node] = part;        // h2[node]
    }
}

// ------------------------- layer 2 aggregate (heads=1, C=1) -------------------------
__global__ void agg2_kernel(const int* __restrict__ row, const int* __restrict__ csr,
                            const float* __restrict__ h2,
                            const float* __restrict__ as2, const float* __restrict__ ad2,
                            const float* __restrict__ b2, float* __restrict__ out, int N)
{
    const int n = blockIdx.x * blockDim.x + threadIdx.x;
    if (n >= N) return;
    const float A_s = as2[0];
    const float hd  = h2[n] * ad2[0];
    const int beg = row[n], end = row[n + 1];
    float den = 0.f, acc = 0.f;
    for (int i = beg; i < end; ++i){
        const float hv = h2[csr[i]];
        float a = fmaf(A_s, hv, hd);
        a = a > 0.f ? a : NEG_SLOPE * a;
        const float p = __expf(a);
        den += p; acc = fmaf(p, hv, acc);
    }
    out[n] = acc / den + b2[0];
}

// =========================================================================
extern "C" void kernel_launch(void* const* d_in, const int* in_sizes, int n_in,
                              void* d_out, int out_size, void* d_ws, size_t ws_size,
                              hipStream_t stream)
{
    const float* x   = (const float*)d_in[0];
    const int*   ei  = (const int*)  d_in[1];
    const float* W0  = (const float*)d_in[2];
    const float* as0 = (const float*)d_in[3];
    const float* ad0 = (const float*)d_in[4];
    const float* b0  = (const float*)d_in[5];
    const float* W1  = (const float*)d_in[6];
    const float* as1 = (const float*)d_in[7];
    const float* ad1 = (const float*)d_in[8];
    const float* b1  = (const float*)d_in[9];
    const float* W2  = (const float*)d_in[10];
    const float* as2 = (const float*)d_in[11];
    const float* ad2 = (const float*)d_in[12];
    const float* b2  = (const float*)d_in[13];
    const float* g0  = (const float*)d_in[14];
    const float* be0 = (const float*)d_in[15];
    const float* m0  = (const float*)d_in[16];
    const float* v0  = (const float*)d_in[17];
    const float* g1  = (const float*)d_in[18];
    const float* be1 = (const float*)d_in[19];
    const float* m1  = (const float*)d_in[20];
    const float* v1  = (const float*)d_in[21];

    const int N = in_sizes[0] / 128;
    const int E = in_sizes[1] / 2;
    const int EN = E + N;

    // ---- workspace layout ----
    char* w = (char*)d_ws;
    unsigned short* H    = (unsigned short*)w;  w += (size_t)N * 256 * 2;  // h bf16 [N][256]
    unsigned short* P0   = (unsigned short*)w;  w += (size_t)N * 256 * 2;  // layer0 out bf16
    float*    asrc   = (float*)w;   w += (size_t)N * 4 * 4;
    float*    adst   = (float*)w;   w += (size_t)N * 4 * 4;
    int*      deg    = (int*)w;     w += (size_t)N * 4;
    int*      cursor = (int*)w;     w += (size_t)N * 4;
    int*      csr    = (int*)w;     w += (size_t)EN * 4;
    float*    h2     = (float*)w;   w += (size_t)N * 4;
    int*      bsum   = (int*)w;     w += 1024;
    unsigned short* Wb0hi = (unsigned short*)w; w += (size_t)128 * 256 * 2;
    unsigned short* Wb0lo = (unsigned short*)w; w += (size_t)128 * 256 * 2;
    unsigned short* Wb1hi = (unsigned short*)w; w += (size_t)256 * 256 * 2;
    unsigned short* Wb1lo = (unsigned short*)w; w += (size_t)256 * 256 * 2;
    int*      rowp   = (int*)w;     w += (size_t)(N + 1) * 4;   // last (odd size)

    const int gN64  = (N + 63) / 64;
    const int gN4   = (N + 3) / 4;
    const int gNt   = (N + 255) / 256;
    const int gE    = (E + 255) / 256;
    const int gEN   = (EN + 255) / 256;
    const int nb    = (N + 1023) / 1024;

    // ---------------- one-time prep: W repack + deg_init (fused), CSR ----------------
    prep_kernel<<<384 + gNt, 256, 0, stream>>>(W0, Wb0hi, Wb0lo, W1, Wb1hi, Wb1lo, deg, N);
    deg_hist_kernel<<<gE, 256, 0, stream>>>(ei, E, deg);
    part_sum_kernel<<<nb, 256, 0, stream>>>(deg, bsum, N);
    scan_part_kernel<<<1, 256, 0, stream>>>(bsum, nb, rowp, N);
    distribute_kernel<<<nb, 256, 0, stream>>>(deg, bsum, rowp, cursor, N);
    scatter_kernel<<<gEN, 256, 0, stream>>>(ei, E, N, cursor, csr);

    // ---------------- layer 0 ----------------
    mfma_gemm0<<<gN64, 256, 0, stream>>>(x, Wb0hi, Wb0lo,
                                         as0, ad0, H, asrc, adst, N);
    agg4_kernel<false><<<gN4, 256, 0, stream>>>(rowp, csr, asrc, adst, H,
                                                b0, g0, be0, m0, v0,
                                                nullptr, P0, nullptr, nullptr, N);

    // ---------------- layer 1 (+ fused h2 = P1 . W2) ----------------
    mfma_gemm1<<<gN64, 256, 0, stream>>>(P0, Wb1hi, Wb1lo,
                                         as1, ad1, H, asrc, adst, N);
    agg4_kernel<true><<<gN4, 256, 0, stream>>>(rowp, csr, asrc, adst, H,
                                               b1, g1, be1, m1, v1,
                                               P0, nullptr, h2, W2, N);

    // ---------------- layer 2 ----------------
    agg2_kernel<<<gNt, 256, 0, stream>>>(rowp, csr, h2, as2, ad2, b2, (float*)d_out, N);
}

// Round 15
// 300.908 us; speedup vs baseline: 1.0792x; 1.0146x over previous
//
#include <hip/hip_runtime.h>
#include <math.h>

#define NEG_SLOPE 0.2f
#define BN_EPS 1e-5f

typedef __attribute__((ext_vector_type(8))) short bf16x8;
typedef __attribute__((ext_vector_type(4))) float f32x4;

static __device__ __forceinline__ unsigned short f2bf(float f){
    unsigned u = __float_as_uint(f);
    u += 0x7FFFu + ((u >> 16) & 1u);          // round-to-nearest-even
    return (unsigned short)(u >> 16);
}
static __device__ __forceinline__ float bf2f(unsigned short v){
    return __uint_as_float((unsigned)v << 16);
}

// async global->LDS, 16B/lane; LDS dest wave-uniform base + lane*16
static __device__ __forceinline__ void gload_lds16(const void* g, void* l){
    __builtin_amdgcn_global_load_lds(
        (const __attribute__((address_space(1))) void*)g,
        (__attribute__((address_space(3))) void*)l, 16, 0, 0);
}

// ---- fused prep: repack W0 (hi/lo), W1 (hi only needed) + deg_init ----
static __device__ __forceinline__ void repack_one(const float* __restrict__ W,
    unsigned short* __restrict__ whi, unsigned short* __restrict__ wlo, int o)
{
    const int j = o & 7, ln = (o >> 3) & 63, ct = (o >> 9) & 15, kt = o >> 13;
    const int k = kt * 32 + 8 * (ln >> 4) + j;
    const int col = ct * 16 + (ln & 15);
    const float v = W[k * 256 + col];
    const unsigned short hb = f2bf(v);
    whi[o] = hb;
    if (wlo) wlo[o] = f2bf(v - bf2f(hb));
}

__global__ void prep_kernel(const float* __restrict__ W0,
    unsigned short* __restrict__ w0hi, unsigned short* __restrict__ w0lo,
    const float* __restrict__ W1,
    unsigned short* __restrict__ w1hi,
    int* __restrict__ deg, int N)
{
    const int bid = blockIdx.x, t = threadIdx.x;
    if (bid < 128){
        repack_one(W0, w0hi, w0lo, bid * 256 + t);
    } else if (bid < 384){
        repack_one(W1, w1hi, nullptr, (bid - 128) * 256 + t);
    } else {
        const int i = (bid - 384) * 256 + t;
        if (i < N) deg[i] = 1;                // self-loop
    }
}

// =========================================================================
// MFMA GEMMs, A-PREFETCH-ALL: whole 64-node A-tile staged to LDS in one shot,
// one barrier, barrier-free kt loop (wave-private B register loads + MFMA).
// gemm0: A = x fp32 hi-plane, W hi/lo (2 MFMA). gemm1: pure bf16 (1 MFMA).
// C/D map (verified): col=lane&15, row=(lane>>4)*4+reg. Wave = head.
// =========================================================================
__global__ __launch_bounds__(256) void mfma_gemm0(
    const float* __restrict__ x,
    const unsigned short* __restrict__ wbhi, const unsigned short* __restrict__ wblo,
    const float* __restrict__ a_s, const float* __restrict__ a_d,
    unsigned short* __restrict__ hout,
    float* __restrict__ asrc, float* __restrict__ adst, int N)
{
    constexpr int K = 128;
    __shared__ float xaf[4][4][2][64][4];     // [kt][rt][half][lane][4] = 32KB
    const int t = threadIdx.x, lane = t & 63, wid = t >> 6;
    const int n0 = blockIdx.x * 64;
    const int l15 = lane & 15, lg = lane >> 4;

    // ---- stage ALL A: 32 issues, 8 per wave ----
#pragma unroll
    for (int ii = 0; ii < 8; ++ii){
        const int i = wid * 8 + ii;
        const int kt = i >> 3, rt = (i >> 1) & 3, half = i & 1;
        int node = n0 + rt * 16 + l15;
        if (node > N - 1) node = N - 1;       // clamp; results discarded later
        const float* src = &x[(size_t)node * K + kt * 32 + 8 * lg + half * 4];
        gload_lds16(src, &xaf[kt][rt][half][0][0]);
    }

    const unsigned short* bph = &wbhi[((size_t)(wid * 4) * 64 + lane) * 8];
    const unsigned short* bpl = &wblo[((size_t)(wid * 4) * 64 + lane) * 8];

    f32x4 acc[4][4];
#pragma unroll
    for (int rt = 0; rt < 4; ++rt)
#pragma unroll
        for (int q = 0; q < 4; ++q) acc[rt][q] = (f32x4){0.f, 0.f, 0.f, 0.f};

    __syncthreads();                          // single drain: A-tile resident

#pragma unroll
    for (int kt = 0; kt < K / 32; ++kt){
        bf16x8 bhi[4], blo[4];
#pragma unroll
        for (int q = 0; q < 4; ++q){
            bhi[q] = *(const bf16x8*)(bph + ((size_t)kt * 16 + q) * 512);
            blo[q] = *(const bf16x8*)(bpl + ((size_t)kt * 16 + q) * 512);
        }
        bf16x8 ahi[4];
#pragma unroll
        for (int rt = 0; rt < 4; ++rt){
            const float4 f0 = *(const float4*)&xaf[kt][rt][0][lane][0];
            const float4 f1 = *(const float4*)&xaf[kt][rt][1][lane][0];
            const float fv[8] = {f0.x, f0.y, f0.z, f0.w, f1.x, f1.y, f1.z, f1.w};
#pragma unroll
            for (int j = 0; j < 8; ++j) ahi[rt][j] = (short)f2bf(fv[j]);
        }
#pragma unroll
        for (int q = 0; q < 4; ++q)
#pragma unroll
            for (int rt = 0; rt < 4; ++rt){
                acc[rt][q] = __builtin_amdgcn_mfma_f32_16x16x32_bf16(ahi[rt], bhi[q], acc[rt][q], 0, 0, 0);
                acc[rt][q] = __builtin_amdgcn_mfma_f32_16x16x32_bf16(ahi[rt], blo[q], acc[rt][q], 0, 0, 0);
            }
    }

    // ---- epilogue: h store + alpha reductions ----
    float avs[4], avd[4];
#pragma unroll
    for (int q = 0; q < 4; ++q){
        avs[q] = a_s[wid * 64 + q * 16 + l15];
        avd[q] = a_d[wid * 64 + q * 16 + l15];
    }
    float sp[4][4], dp[4][4];
#pragma unroll
    for (int rt = 0; rt < 4; ++rt){
#pragma unroll
        for (int reg = 0; reg < 4; ++reg){
            const int node = n0 + rt * 16 + lg * 4 + reg;
            float s = 0.f, d = 0.f;
            unsigned short hv[4];
#pragma unroll
            for (int q = 0; q < 4; ++q){
                const float v = acc[rt][q][reg];
                s = fmaf(v, avs[q], s); d = fmaf(v, avd[q], d);
                hv[q] = f2bf(v);
            }
            if (node < N){
#pragma unroll
                for (int q = 0; q < 4; ++q)
                    hout[(size_t)node * 256 + (wid * 4 + q) * 16 + l15] = hv[q];
            }
            sp[rt][reg] = s; dp[rt][reg] = d;
        }
    }
#pragma unroll
    for (int off = 1; off <= 8; off <<= 1){
#pragma unroll
        for (int rt = 0; rt < 4; ++rt)
#pragma unroll
            for (int reg = 0; reg < 4; ++reg){
                sp[rt][reg] += __shfl_xor(sp[rt][reg], off, 64);
                dp[rt][reg] += __shfl_xor(dp[rt][reg], off, 64);
            }
    }
    if (l15 == 0){
#pragma unroll
        for (int rt = 0; rt < 4; ++rt)
#pragma unroll
            for (int reg = 0; reg < 4; ++reg){
                const int node = n0 + rt * 16 + lg * 4 + reg;
                if (node < N){
                    asrc[(size_t)node * 4 + wid] = sp[rt][reg];
                    adst[(size_t)node * 4 + wid] = dp[rt][reg];
                }
            }
    }
}

__global__ __launch_bounds__(256) void mfma_gemm1(
    const unsigned short* __restrict__ xb,
    const unsigned short* __restrict__ wbhi,
    const float* __restrict__ a_s, const float* __restrict__ a_d,
    unsigned short* __restrict__ hout,
    float* __restrict__ asrc, float* __restrict__ adst, int N)
{
    constexpr int K = 256;
    __shared__ unsigned short xab[8][4][512]; // [kt][rt][lane*8] = 32KB
    const int t = threadIdx.x, lane = t & 63, wid = t >> 6;
    const int n0 = blockIdx.x * 64;
    const int l15 = lane & 15, lg = lane >> 4;

    // ---- stage ALL A: 32 issues, 8 per wave ----
#pragma unroll
    for (int ii = 0; ii < 8; ++ii){
        const int i = wid * 8 + ii;
        const int kt = i >> 2, rt = i & 3;
        int node = n0 + rt * 16 + l15;
        if (node > N - 1) node = N - 1;
        const unsigned short* src = &xb[(size_t)node * K + kt * 32 + 8 * lg];
        gload_lds16(src, &xab[kt][rt][0]);
    }

    const unsigned short* bph = &wbhi[((size_t)(wid * 4) * 64 + lane) * 8];

    f32x4 acc[4][4];
#pragma unroll
    for (int rt = 0; rt < 4; ++rt)
#pragma unroll
        for (int q = 0; q < 4; ++q) acc[rt][q] = (f32x4){0.f, 0.f, 0.f, 0.f};

    __syncthreads();                          // single drain: A-tile resident

#pragma unroll
    for (int kt = 0; kt < K / 32; ++kt){
        bf16x8 bhi[4];
#pragma unroll
        for (int q = 0; q < 4; ++q)
            bhi[q] = *(const bf16x8*)(bph + ((size_t)kt * 16 + q) * 512);
        bf16x8 a[4];
#pragma unroll
        for (int rt = 0; rt < 4; ++rt)
            a[rt] = *(const bf16x8*)&xab[kt][rt][lane * 8];

#pragma unroll
        for (int q = 0; q < 4; ++q)
#pragma unroll
            for (int rt = 0; rt < 4; ++rt)
                acc[rt][q] = __builtin_amdgcn_mfma_f32_16x16x32_bf16(a[rt], bhi[q], acc[rt][q], 0, 0, 0);
    }

    // ---- epilogue ----
    float avs[4], avd[4];
#pragma unroll
    for (int q = 0; q < 4; ++q){
        avs[q] = a_s[wid * 64 + q * 16 + l15];
        avd[q] = a_d[wid * 64 + q * 16 + l15];
    }
    float sp[4][4], dp[4][4];
#pragma unroll
    for (int rt = 0; rt < 4; ++rt){
#pragma unroll
        for (int reg = 0; reg < 4; ++reg){
            const int node = n0 + rt * 16 + lg * 4 + reg;
            float s = 0.f, d = 0.f;
            unsigned short hv[4];
#pragma unroll
            for (int q = 0; q < 4; ++q){
                const float v = acc[rt][q][reg];
                s = fmaf(v, avs[q], s); d = fmaf(v, avd[q], d);
                hv[q] = f2bf(v);
            }
            if (node < N){
#pragma unroll
                for (int q = 0; q < 4; ++q)
                    hout[(size_t)node * 256 + (wid * 4 + q) * 16 + l15] = hv[q];
            }
            sp[rt][reg] = s; dp[rt][reg] = d;
        }
    }
#pragma unroll
    for (int off = 1; off <= 8; off <<= 1){
#pragma unroll
        for (int rt = 0; rt < 4; ++rt)
#pragma unroll
            for (int reg = 0; reg < 4; ++reg){
                sp[rt][reg] += __shfl_xor(sp[rt][reg], off, 64);
                dp[rt][reg] += __shfl_xor(dp[rt][reg], off, 64);
            }
    }
    if (l15 == 0){
#pragma unroll
        for (int rt = 0; rt < 4; ++rt)
#pragma unroll
            for (int reg = 0; reg < 4; ++reg){
                const int node = n0 + rt * 16 + lg * 4 + reg;
                if (node < N){
                    asrc[(size_t)node * 4 + wid] = sp[rt][reg];
                    adst[(size_t)node * 4 + wid] = dp[rt][reg];
                }
            }
    }
}

// ============================ CSR build (once) ============================
__global__ void deg_hist_kernel(const int* __restrict__ ei, int E, int* __restrict__ deg){
    int e = blockIdx.x * blockDim.x + threadIdx.x;
    if (e < E) atomicAdd(&deg[ei[E + e]], 1);
}

__global__ __launch_bounds__(256) void part_sum_kernel(const int* __restrict__ deg,
                                                       int* __restrict__ bsum, int N)
{
    __shared__ int red[256];
    const int t = threadIdx.x;
    const int i0 = blockIdx.x * 1024 + t * 4;
    int s = 0;
    if (i0 + 3 < N){
        const int4 v = *(const int4*)&deg[i0];
        s = v.x + v.y + v.z + v.w;
    } else {
#pragma unroll
        for (int j = 0; j < 4; ++j) if (i0 + j < N) s += deg[i0 + j];
    }
    red[t] = s; __syncthreads();
    for (int off = 128; off >= 1; off >>= 1){
        if (t < off) red[t] += red[t + off];
        __syncthreads();
    }
    if (t == 0) bsum[blockIdx.x] = red[0];
}

__global__ __launch_bounds__(256) void scan_part_kernel(int* __restrict__ bsum, int nb,
                                                        int* __restrict__ row, int N)
{
    __shared__ int sh[256];
    const int t = threadIdx.x;
    const int v = (t < nb) ? bsum[t] : 0;
    sh[t] = v; __syncthreads();
    for (int off = 1; off < 256; off <<= 1){
        int u = (t >= off) ? sh[t - off] : 0;
        __syncthreads();
        sh[t] += u;
        __syncthreads();
    }
    if (t < nb) bsum[t] = sh[t] - v;              // exclusive
    if (t == nb - 1) row[N] = sh[t];              // total = E + N
}

__global__ __launch_bounds__(256) void distribute_kernel(const int* __restrict__ deg,
    const int* __restrict__ bsum, int* __restrict__ row, int* __restrict__ cursor, int N)
{
    __shared__ int ts[256];
    const int t = threadIdx.x;
    const int i0 = blockIdx.x * 1024 + t * 4;
    int d[4]; int s = 0;
#pragma unroll
    for (int j = 0; j < 4; ++j){ d[j] = (i0 + j < N) ? deg[i0 + j] : 0; s += d[j]; }
    ts[t] = s; __syncthreads();
    for (int off = 1; off < 256; off <<= 1){
        int u = (t >= off) ? ts[t - off] : 0;
        __syncthreads();
        ts[t] += u;
        __syncthreads();
    }
    int base = bsum[blockIdx.x] + ts[t] - s;
#pragma unroll
    for (int j = 0; j < 4; ++j){
        if (i0 + j < N){ row[i0 + j] = base; cursor[i0 + j] = base; base += d[j]; }
    }
}

__global__ void scatter_kernel(const int* __restrict__ ei, int E, int N,
                               int* __restrict__ cursor, int* __restrict__ csr)
{
    int e = blockIdx.x * blockDim.x + threadIdx.x;
    if (e >= E + N) return;
    int s, d;
    if (e < E){ s = ei[e]; d = ei[E + e]; } else { s = d = e - E; }
    int pos = atomicAdd(&cursor[d], 1);
    csr[pos] = s;
}

// =========================================================================
// Gather-aggregate: one wave per node, 4 waves/block. h [node][256] bf16;
// lane owns (head = lane>>4, channels 4*lane..4*lane+3).
// Phase A: lane-parallel p=exp(leakyrelu(e)) -> LDS + denom butterfly.
// Phase B: 2-unrolled gather via byte offsets (VGPR-lean, 70% occ).
//   LAST=false: write P0 bf16. LAST=true: +res, h2 = P1.W2 -> outh2[node].
// =========================================================================
#define DEG_CAP 128
template<bool LAST>
__global__ __launch_bounds__(256) void agg4_kernel(
    const int* __restrict__ row, const int* __restrict__ csr,
    const float* __restrict__ asrc, const float* __restrict__ adst,
    const unsigned short* __restrict__ h,
    const float* __restrict__ b, const float* __restrict__ g,
    const float* __restrict__ be, const float* __restrict__ mean,
    const float* __restrict__ var,
    const unsigned short* __restrict__ res,   // bf16 residual (LAST only)
    unsigned short* __restrict__ outbf,       // P0 bf16 (layer0)
    float* __restrict__ outh2,                // h2 (LAST)
    const float* __restrict__ W2,             // LAST only
    int N)
{
    __shared__ float plds[4][DEG_CAP * 4];
    __shared__ int   slds[4][DEG_CAP];
    const int wid = threadIdx.x >> 6, lane = threadIdx.x & 63;
    const int node = blockIdx.x * 4 + wid;
    if (node >= N) return;
    const int beg = row[node], end = row[node + 1], deg = end - beg;
    const int degc = deg < DEG_CAP ? deg : DEG_CAP;
    const int head = lane >> 4;

    const float4 ad = *(const float4*)&adst[(size_t)node * 4];

    // ---- phase A ----
    float d0 = 0.f, d1 = 0.f, d2 = 0.f, d3 = 0.f;
    for (int i = lane; i < deg; i += 64){
        const int s = csr[beg + i];
        const float4 as = *(const float4*)&asrc[(size_t)s * 4];
        float v0 = as.x + ad.x, v1 = as.y + ad.y, v2 = as.z + ad.z, v3 = as.w + ad.w;
        v0 = v0 > 0.f ? v0 : NEG_SLOPE * v0;
        v1 = v1 > 0.f ? v1 : NEG_SLOPE * v1;
        v2 = v2 > 0.f ? v2 : NEG_SLOPE * v2;
        v3 = v3 > 0.f ? v3 : NEG_SLOPE * v3;
        const float p0 = __expf(v0), p1 = __expf(v1);
        const float p2 = __expf(v2), p3 = __expf(v3);
        d0 += p0; d1 += p1; d2 += p2; d3 += p3;
        if (i < DEG_CAP){
            *(float4*)&plds[wid][i * 4] = make_float4(p0, p1, p2, p3);
            slds[wid][i] = s << 9;               // byte offset of h row
        }
    }
    for (int off = 32; off >= 1; off >>= 1){
        d0 += __shfl_xor(d0, off, 64); d1 += __shfl_xor(d1, off, 64);
        d2 += __shfl_xor(d2, off, 64); d3 += __shfl_xor(d3, off, 64);
    }

    // ---- phase B: 2-unrolled weighted gather-accumulate ----
    float a0 = 0.f, a1 = 0.f, a2 = 0.f, a3 = 0.f;
    {
        const char* hb = (const char*)h + lane * 8;
        const float* pb = &plds[wid][0];
        const int* sb = &slds[wid][0];
#define EDGE_BODY(slot)                                                        \
        {                                                                      \
            const float p_ = pb[(slot) * 4 + head];                            \
            const ushort4 hv_ = *(const ushort4*)(hb + sb[slot]);              \
            a0 = fmaf(p_, bf2f(hv_.x), a0); a1 = fmaf(p_, bf2f(hv_.y), a1);    \
            a2 = fmaf(p_, bf2f(hv_.z), a2); a3 = fmaf(p_, bf2f(hv_.w), a3);    \
        }
        int i = 0;
        for (; i + 2 <= degc; i += 2){
            EDGE_BODY(i);
            EDGE_BODY(i + 1);
        }
        for (; i < degc; ++i) EDGE_BODY(i);
#undef EDGE_BODY
    }

    // overflow path (deg > DEG_CAP): statistically never
    for (int jj = beg + DEG_CAP; jj < end; ++jj){
        const int s = csr[jj];
        const float4 as = *(const float4*)&asrc[(size_t)s * 4];
        float e0 = as.x + ad.x, e1 = as.y + ad.y, e2 = as.z + ad.z, e3 = as.w + ad.w;
        float eh = (head == 0) ? e0 : (head == 1) ? e1 : (head == 2) ? e2 : e3;
        eh = eh > 0.f ? eh : NEG_SLOPE * eh;
        const float p = __expf(eh);
        const ushort4 hv = *(const ushort4*)&h[(size_t)s * 256 + lane * 4];
        a0 = fmaf(p, bf2f(hv.x), a0); a1 = fmaf(p, bf2f(hv.y), a1);
        a2 = fmaf(p, bf2f(hv.z), a2); a3 = fmaf(p, bf2f(hv.w), a3);
    }

    // ---- fused epilogue ----
    const int l15 = lane & 15;
    const float dsel = (head == 0) ? d0 : (head == 1) ? d1 : (head == 2) ? d2 : d3;
    const float rdi = 1.f / dsel;
    const int c0 = head * 64 + 4 * l15;
    const float4 bv  = *(const float4*)&b[c0];
    const float4 gv  = *(const float4*)&g[c0];
    const float4 bev = *(const float4*)&be[c0];
    const float4 mv  = *(const float4*)&mean[c0];
    const float4 vv4 = *(const float4*)&var[c0];
    const float ava[4]  = {a0, a1, a2, a3};
    const float bva[4]  = {bv.x, bv.y, bv.z, bv.w};
    const float gva[4]  = {gv.x, gv.y, gv.z, gv.w};
    const float beva[4] = {bev.x, bev.y, bev.z, bev.w};
    const float mva[4]  = {mv.x, mv.y, mv.z, mv.w};
    const float vva[4]  = {vv4.x, vv4.y, vv4.z, vv4.w};
    float rh[4] = {0.f, 0.f, 0.f, 0.f};
    if (LAST){
        const ushort4 rv = *(const ushort4*)&res[(size_t)node * 256 + c0];
        rh[0] = bf2f(rv.x); rh[1] = bf2f(rv.y); rh[2] = bf2f(rv.z); rh[3] = bf2f(rv.w);
    }
    float vvv[4];
#pragma unroll
    for (int j = 0; j < 4; ++j){
        float v = ava[j] * rdi + bva[j];
        v = (v - mva[j]) * (gva[j] * rsqrtf(vva[j] + BN_EPS)) + beva[j];
        v = v > 0.f ? v : (__expf(v) - 1.f);
        vvv[j] = v + rh[j];
    }
    if (!LAST){
        ushort4 o4;
        o4.x = f2bf(vvv[0]); o4.y = f2bf(vvv[1]);
        o4.z = f2bf(vvv[2]); o4.w = f2bf(vvv[3]);
        *(ushort4*)&outbf[(size_t)node * 256 + c0] = o4;
    } else {
        const float4 w2v = *(const float4*)&W2[c0];
        float part = vvv[0] * w2v.x + vvv[1] * w2v.y + vvv[2] * w2v.z + vvv[3] * w2v.w;
        for (int off = 32; off >= 1; off >>= 1) part += __shfl_xor(part, off, 64);
        if (lane == 0) outh2[node] = part;        // h2[node]
    }
}

// ------------------------- layer 2 aggregate (heads=1, C=1) -------------------------
__global__ void agg2_kernel(const int* __restrict__ row, const int* __restrict__ csr,
                            const float* __restrict__ h2,
                            const float* __restrict__ as2, const float* __restrict__ ad2,
                            const float* __restrict__ b2, float* __restrict__ out, int N)
{
    const int n = blockIdx.x * blockDim.x + threadIdx.x;
    if (n >= N) return;
    const float A_s = as2[0];
    const float hd  = h2[n] * ad2[0];
    const int beg = row[n], end = row[n + 1];
    float den = 0.f, acc = 0.f;
    for (int i = beg; i < end; ++i){
        const float hv = h2[csr[i]];
        float a = fmaf(A_s, hv, hd);
        a = a > 0.f ? a : NEG_SLOPE * a;
        const float p = __expf(a);
        den += p; acc = fmaf(p, hv, acc);
    }
    out[n] = acc / den + b2[0];
}

// =========================================================================
extern "C" void kernel_launch(void* const* d_in, const int* in_sizes, int n_in,
                              void* d_out, int out_size, void* d_ws, size_t ws_size,
                              hipStream_t stream)
{
    const float* x   = (const float*)d_in[0];
    const int*   ei  = (const int*)  d_in[1];
    const float* W0  = (const float*)d_in[2];
    const float* as0 = (const float*)d_in[3];
    const float* ad0 = (const float*)d_in[4];
    const float* b0  = (const float*)d_in[5];
    const float* W1  = (const float*)d_in[6];
    const float* as1 = (const float*)d_in[7];
    const float* ad1 = (const float*)d_in[8];
    const float* b1  = (const float*)d_in[9];
    const float* W2  = (const float*)d_in[10];
    const float* as2 = (const float*)d_in[11];
    const float* ad2 = (const float*)d_in[12];
    const float* b2  = (const float*)d_in[13];
    const float* g0  = (const float*)d_in[14];
    const float* be0 = (const float*)d_in[15];
    const float* m0  = (const float*)d_in[16];
    const float* v0  = (const float*)d_in[17];
    const float* g1  = (const float*)d_in[18];
    const float* be1 = (const float*)d_in[19];
    const float* m1  = (const float*)d_in[20];
    const float* v1  = (const float*)d_in[21];

    const int N = in_sizes[0] / 128;
    const int E = in_sizes[1] / 2;
    const int EN = E + N;

    // ---- workspace layout ----
    char* w = (char*)d_ws;
    unsigned short* H    = (unsigned short*)w;  w += (size_t)N * 256 * 2;  // h bf16 [N][256]
    unsigned short* P0   = (unsigned short*)w;  w += (size_t)N * 256 * 2;  // layer0 out bf16
    float*    asrc   = (float*)w;   w += (size_t)N * 4 * 4;
    float*    adst   = (float*)w;   w += (size_t)N * 4 * 4;
    int*      deg    = (int*)w;     w += (size_t)N * 4;
    int*      cursor = (int*)w;     w += (size_t)N * 4;
    int*      csr    = (int*)w;     w += (size_t)EN * 4;
    float*    h2     = (float*)w;   w += (size_t)N * 4;
    int*      bsum   = (int*)w;     w += 1024;
    unsigned short* Wb0hi = (unsigned short*)w; w += (size_t)128 * 256 * 2;
    unsigned short* Wb0lo = (unsigned short*)w; w += (size_t)128 * 256 * 2;
    unsigned short* Wb1hi = (unsigned short*)w; w += (size_t)256 * 256 * 2;
    int*      rowp   = (int*)w;     w += (size_t)(N + 1) * 4;   // last (odd size)

    const int gN64  = (N + 63) / 64;
    const int gN4   = (N + 3) / 4;
    const int gNt   = (N + 255) / 256;
    const int gE    = (E + 255) / 256;
    const int gEN   = (EN + 255) / 256;
    const int nb    = (N + 1023) / 1024;

    // ---------------- one-time prep: W repack + deg_init (fused), CSR ----------------
    prep_kernel<<<384 + gNt, 256, 0, stream>>>(W0, Wb0hi, Wb0lo, W1, Wb1hi, deg, N);
    deg_hist_kernel<<<gE, 256, 0, stream>>>(ei, E, deg);
    part_sum_kernel<<<nb, 256, 0, stream>>>(deg, bsum, N);
    scan_part_kernel<<<1, 256, 0, stream>>>(bsum, nb, rowp, N);
    distribute_kernel<<<nb, 256, 0, stream>>>(deg, bsum, rowp, cursor, N);
    scatter_kernel<<<gEN, 256, 0, stream>>>(ei, E, N, cursor, csr);

    // ---------------- layer 0 ----------------
    mfma_gemm0<<<gN64, 256, 0, stream>>>(x, Wb0hi, Wb0lo,
                                         as0, ad0, H, asrc, adst, N);
    agg4_kernel<false><<<gN4, 256, 0, stream>>>(rowp, csr, asrc, adst, H,
                                                b0, g0, be0, m0, v0,
                                                nullptr, P0, nullptr, nullptr, N);

    // ---------------- layer 1 (+ fused h2 = P1 . W2) ----------------
    mfma_gemm1<<<gN64, 256, 0, stream>>>(P0, Wb1hi,
                                         as1, ad1, H, asrc, adst, N);
    agg4_kernel<true><<<gN4, 256, 0, stream>>>(rowp, csr, asrc, adst, H,
                                               b1, g1, be1, m1, v1,
                                               P0, nullptr, h2, W2, N);

    // ---------------- layer 2 ----------------
    agg2_kernel<<<gNt, 256, 0, stream>>>(rowp, csr, h2, as2, ad2, b2, (float*)d_out, N);
}